// Round 2
// baseline (11487.744 us; speedup 1.0000x reference)
//
#include <hip/hip_runtime.h>
#include <hip/hip_bf16.h>

#define BB 64
#define TT 100
#define KSEL 2048
#define EMBD 300
#define HH 512
#define GG 2048   // 4*H
#define NSYN 16

// ---------------- W_hh transpose+permute prep ----------------
// WT[k][j*4+q] = W[q*512+j][k]  (512 x 2048), so lstm reads row k as
// coalesced float4s: lane j reads WT[k][4j..4j+4) = gates (i,f,g,o) of hidden j.
__global__ void whhT_kernel(const float* __restrict__ w0f, const float* __restrict__ w0b,
                            const float* __restrict__ w1f, const float* __restrict__ w1b,
                            float* __restrict__ t0f, float* __restrict__ t0b,
                            float* __restrict__ t1f, float* __restrict__ t1b) {
    __shared__ float tile[64][65];
    int arr = blockIdx.x >> 8;
    int blk = blockIdx.x & 255;
    int kt = blk >> 5, nt = blk & 31;
    const float* W = arr == 0 ? w0f : arr == 1 ? w0b : arr == 2 ? w1f : w1b;
    float* O = arr == 0 ? t0f : arr == 1 ? t0b : arr == 2 ? t1f : t1b;
    int tid = threadIdx.x;
    for (int e = tid; e < 4096; e += 256) {
        int rl = e >> 6, kl = e & 63;
        int np = nt * 64 + rl;
        int row = (np & 3) * 512 + (np >> 2);
        tile[rl][kl] = W[(size_t)row * 512 + kt * 64 + kl];
    }
    __syncthreads();
    for (int e = tid; e < 4096; e += 256) {
        int kl = e >> 6, rl = e & 63;
        O[(size_t)(kt * 64 + kl) * 2048 + nt * 64 + rl] = tile[rl][kl];
    }
}

// ---------------- layer-0 input projection (embedding fused) ----------------
// gates[(t*64+b)*2048 + n'],  n' = j*4+q,  row pr = q*512+j
__global__ void xproj_l0_kernel(const int* __restrict__ X, const float* __restrict__ emb,
                                const float* __restrict__ W, const float* __restrict__ bih,
                                const float* __restrict__ bhh, float* __restrict__ gates) {
    __shared__ float As[16][68];
    __shared__ float Bs[16][68];
    __shared__ int rid[64];
    int tid = threadIdx.x;
    int m0 = blockIdx.x * 64, n0 = blockIdx.y * 64;
    if (tid < 64) rid[tid] = X[m0 + tid];   // m = b*100 + t
    __syncthreads();
    int tx = tid & 15, ty = tid >> 4;
    float acc[4][4] = {};
    for (int k0 = 0; k0 < 304; k0 += 16) {
        for (int e = tid; e < 1024; e += 256) {
            int ml = e >> 4, k = e & 15;
            int kk = k0 + k;
            As[k][ml] = (kk < EMBD) ? emb[(size_t)rid[ml] * EMBD + kk] : 0.f;
        }
        for (int e = tid; e < 1024; e += 256) {
            int nl = e >> 4, k = e & 15;
            int n = n0 + nl;
            int pr = (n & 3) * 512 + (n >> 2);
            int kk = k0 + k;
            Bs[k][nl] = (kk < EMBD) ? W[(size_t)pr * EMBD + kk] : 0.f;
        }
        __syncthreads();
#pragma unroll
        for (int kk = 0; kk < 16; kk++) {
            float4 a4 = *(const float4*)&As[kk][ty * 4];
            float4 b4 = *(const float4*)&Bs[kk][tx * 4];
            float av[4] = {a4.x, a4.y, a4.z, a4.w};
            float bv[4] = {b4.x, b4.y, b4.z, b4.w};
#pragma unroll
            for (int i = 0; i < 4; i++)
#pragma unroll
                for (int j = 0; j < 4; j++) acc[i][j] += av[i] * bv[j];
        }
        __syncthreads();
    }
    for (int i = 0; i < 4; i++) {
        int m = m0 + ty * 4 + i;
        int bidx = m / 100;
        int t = m - bidx * 100;
        size_t base = ((size_t)(t * 64 + bidx)) * GG;
        for (int j = 0; j < 4; j++) {
            int n = n0 + tx * 4 + j;
            int pr = (n & 3) * 512 + (n >> 2);
            gates[base + n] = acc[i][j] + bih[pr] + bhh[pr];
        }
    }
}

// ---------------- layer-1 input projection (bf16 A = hseq0 [t][1024][64]) ----------------
__global__ void xproj_l1_kernel(const __hip_bfloat16* __restrict__ A, const float* __restrict__ W,
                                const float* __restrict__ bih, const float* __restrict__ bhh,
                                float* __restrict__ gates) {
    __shared__ float As[16][68];
    __shared__ float Bs[16][68];
    int tid = threadIdx.x;
    int m0 = blockIdx.x * 64, n0 = blockIdx.y * 64;
    int t = m0 >> 6;
    int tx = tid & 15, ty = tid >> 4;
    float acc[4][4] = {};
    for (int k0 = 0; k0 < 1024; k0 += 16) {
        for (int e = tid; e < 1024; e += 256) {
            int k = e >> 6, ml = e & 63;
            As[k][ml] = __bfloat162float(A[((size_t)t * 1024 + k0 + k) * 64 + ml]);
        }
        for (int e = tid; e < 1024; e += 256) {
            int nl = e >> 4, k = e & 15;
            int n = n0 + nl;
            int pr = (n & 3) * 512 + (n >> 2);
            Bs[k][nl] = W[(size_t)pr * 1024 + k0 + k];
        }
        __syncthreads();
#pragma unroll
        for (int kk = 0; kk < 16; kk++) {
            float4 a4 = *(const float4*)&As[kk][ty * 4];
            float4 b4 = *(const float4*)&Bs[kk][tx * 4];
            float av[4] = {a4.x, a4.y, a4.z, a4.w};
            float bv[4] = {b4.x, b4.y, b4.z, b4.w};
#pragma unroll
            for (int i = 0; i < 4; i++)
#pragma unroll
                for (int j = 0; j < 4; j++) acc[i][j] += av[i] * bv[j];
        }
        __syncthreads();
    }
    for (int i = 0; i < 4; i++) {
        int m = m0 + ty * 4 + i;
        size_t base = (size_t)m * GG;
        for (int j = 0; j < 4; j++) {
            int n = n0 + tx * 4 + j;
            int pr = (n & 3) * 512 + (n >> 2);
            gates[base + n] = acc[i][j] + bih[pr] + bhh[pr];
        }
    }
}

__device__ __forceinline__ float sigf(float x) { return 1.f / (1.f + __expf(-x)); }
__device__ __forceinline__ float tanhfast(float x) {
    float e = __expf(-2.f * fabsf(x));
    float r = (1.f - e) / (1.f + e);
    return copysignf(r, x);
}

// ---------------- batch-parallel bilstm layer: NO grid sync ----------------
// 64 wgs x 512 threads. dir partitioned by XCD (bid%8: 0-3 fwd, 4-7 bwd) so each
// XCD's L2 holds one dir's 4MB WT. Each wg owns 2 whole batches for the entire
// time loop; h double-buffered in LDS; W streamed from L2 every step.
// thread tid = hidden dim j; owns gates float4 (i,f,g,o) at n' = 4j.
template<int MODE>
__global__ void __launch_bounds__(512)
lstm_bp_kernel(const float* __restrict__ gates_f, const float* __restrict__ gates_b,
               const float* __restrict__ wt_f, const float* __restrict__ wt_b,
               const int* __restrict__ lengths, void* __restrict__ hseq_out) {
    __shared__ float hl[2][2][512];
    int bid = blockIdx.x;
    int xcd = bid & 7;
    int dir = (xcd >= 4) ? 1 : 0;
    int rank = (bid >> 3) * 4 + (xcd & 3);   // 0..31 within dir
    int b0 = rank * 2;
    int tid = threadIdx.x;                    // j = tid
    const float* g = dir ? gates_b : gates_f;
    const float4* wt = (const float4*)(dir ? wt_b : wt_f) + tid;  // row k at offset k*512
    hl[0][0][tid] = 0.f; hl[0][1][tid] = 0.f;
    hl[1][0][tid] = 0.f; hl[1][1][tid] = 0.f;
    float c0 = 0.f, c1 = 0.f, h0 = 0.f, h1 = 0.f;
    int len0 = lengths[b0], len1 = lengths[b0 + 1];
    __syncthreads();
    int cur = 0;
    for (int s = 0; s < TT; s++) {
        int t = dir ? (TT - 1 - s) : s;
        float4 acc0 = *(const float4*)(g + ((size_t)(t * 64 + b0)) * GG + tid * 4);
        float4 acc1 = *(const float4*)(g + ((size_t)(t * 64 + b0 + 1)) * GG + tid * 4);
        const float* ha = hl[cur][0];
        const float* hb = hl[cur][1];
#pragma unroll 4
        for (int k = 0; k < 512; k += 4) {
            float4 h4a = *(const float4*)(ha + k);
            float4 h4b = *(const float4*)(hb + k);
            float4 w0 = wt[(size_t)(k + 0) * 512];
            float4 w1 = wt[(size_t)(k + 1) * 512];
            float4 w2 = wt[(size_t)(k + 2) * 512];
            float4 w3 = wt[(size_t)(k + 3) * 512];
            acc0.x += h4a.x * w0.x; acc0.y += h4a.x * w0.y; acc0.z += h4a.x * w0.z; acc0.w += h4a.x * w0.w;
            acc1.x += h4b.x * w0.x; acc1.y += h4b.x * w0.y; acc1.z += h4b.x * w0.z; acc1.w += h4b.x * w0.w;
            acc0.x += h4a.y * w1.x; acc0.y += h4a.y * w1.y; acc0.z += h4a.y * w1.z; acc0.w += h4a.y * w1.w;
            acc1.x += h4b.y * w1.x; acc1.y += h4b.y * w1.y; acc1.z += h4b.y * w1.z; acc1.w += h4b.y * w1.w;
            acc0.x += h4a.z * w2.x; acc0.y += h4a.z * w2.y; acc0.z += h4a.z * w2.z; acc0.w += h4a.z * w2.w;
            acc1.x += h4b.z * w2.x; acc1.y += h4b.z * w2.y; acc1.z += h4b.z * w2.z; acc1.w += h4b.z * w2.w;
            acc0.x += h4a.w * w3.x; acc0.y += h4a.w * w3.y; acc0.z += h4a.w * w3.z; acc0.w += h4a.w * w3.w;
            acc1.x += h4b.w * w3.x; acc1.y += h4b.w * w3.y; acc1.z += h4b.w * w3.z; acc1.w += h4b.w * w3.w;
        }
        {
            float i_s = sigf(acc0.x), f_s = sigf(acc0.y), g_t = tanhfast(acc0.z), o_s = sigf(acc0.w);
            float c_new = f_s * c0 + i_s * g_t;
            float h_new = o_s * tanhfast(c_new);
            if (t < len0) { c0 = c_new; h0 = h_new; }
        }
        {
            float i_s = sigf(acc1.x), f_s = sigf(acc1.y), g_t = tanhfast(acc1.z), o_s = sigf(acc1.w);
            float c_new = f_s * c1 + i_s * g_t;
            float h_new = o_s * tanhfast(c_new);
            if (t < len1) { c1 = c_new; h1 = h_new; }
        }
        hl[cur ^ 1][0][tid] = h0;
        hl[cur ^ 1][1][tid] = h1;
        if (MODE == 0) {
            __hip_bfloat16* o = (__hip_bfloat16*)hseq_out;   // [t][1024][64] bf16
            o[((size_t)t * 1024 + dir * 512 + tid) * 64 + b0] = __float2bfloat16(h0);
            o[((size_t)t * 1024 + dir * 512 + tid) * 64 + b0 + 1] = __float2bfloat16(h1);
        } else {
            float* o = (float*)hseq_out;                      // [b][t][1024] f32
            o[((size_t)b0 * TT + t) * 1024 + dir * 512 + tid] = h0;
            o[((size_t)(b0 + 1) * TT + t) * 1024 + dir * 512 + tid] = h1;
        }
        cur ^= 1;
        __syncthreads();
    }
}

// ---------------- ctx = xsel @ out_W^T + out_b ----------------
__global__ void ctx_kernel(const float* __restrict__ hseq1, const float* __restrict__ outW,
                           const float* __restrict__ outb, const int* __restrict__ sel_b,
                           const int* __restrict__ sel_t, float* __restrict__ out) {
    __shared__ float As[16][68];
    __shared__ float Bs[16][68];
    __shared__ int rowbase[64];
    int tid = threadIdx.x;
    int m0 = blockIdx.x * 64, n0 = blockIdx.y * 64;
    if (tid < 64) {
        int m = m0 + tid;
        rowbase[tid] = (sel_b[m] * TT + sel_t[m]) * 1024;
    }
    __syncthreads();
    int tx = tid & 15, ty = tid >> 4;
    float acc[4][4] = {};
    for (int k0 = 0; k0 < 1024; k0 += 16) {
        for (int e = tid; e < 1024; e += 256) {
            int ml = e >> 4, k = e & 15;
            As[k][ml] = hseq1[(size_t)rowbase[ml] + k0 + k];
        }
        for (int e = tid; e < 1024; e += 256) {
            int nl = e >> 4, k = e & 15;
            int n = n0 + nl;
            Bs[k][nl] = (n < EMBD) ? outW[(size_t)n * 1024 + k0 + k] : 0.f;
        }
        __syncthreads();
#pragma unroll
        for (int kk = 0; kk < 16; kk++) {
            float4 a4 = *(const float4*)&As[kk][ty * 4];
            float4 b4 = *(const float4*)&Bs[kk][tx * 4];
            float av[4] = {a4.x, a4.y, a4.z, a4.w};
            float bv[4] = {b4.x, b4.y, b4.z, b4.w};
#pragma unroll
            for (int i = 0; i < 4; i++)
#pragma unroll
                for (int j = 0; j < 4; j++) acc[i][j] += av[i] * bv[j];
        }
        __syncthreads();
    }
    for (int i = 0; i < 4; i++) {
        int m = m0 + ty * 4 + i;
        for (int j = 0; j < 4; j++) {
            int n = n0 + tx * 4 + j;
            if (n < EMBD) out[(size_t)m * EMBD + n] = acc[i][j] + outb[n];
        }
    }
}

// ---------------- cls = einsum('ksd,kd->ks', exp_W[eidx], xsel) + exp_b[eidx] ----------------
__global__ void cls_kernel(const float* __restrict__ hseq1, const float* __restrict__ expW,
                           const float* __restrict__ expb, const int* __restrict__ sel_b,
                           const int* __restrict__ sel_t, const int* __restrict__ eidx,
                           float* __restrict__ out) {
    __shared__ float xr[1024];
    int r = blockIdx.x;
    int tid = threadIdx.x;
    int e = eidx[r];
    int base = (sel_b[r] * TT + sel_t[r]) * 1024;
    for (int q = tid; q < 1024; q += 256) xr[q] = hseq1[(size_t)base + q];
    __syncthreads();
    int lane = tid & 63, wid = tid >> 6;
    for (int p = 0; p < 4; p++) {
        int s = p * 4 + wid;
        const float* wrow = expW + ((size_t)e * NSYN + s) * 1024;
        float partial = 0.f;
#pragma unroll
        for (int i = 0; i < 16; i++) {
            int k = lane + 64 * i;
            partial += xr[k] * wrow[k];
        }
        for (int off = 32; off; off >>= 1) partial += __shfl_down(partial, off);
        if (lane == 0) out[(size_t)KSEL * EMBD + (size_t)r * NSYN + s] = partial + expb[e * NSYN + s];
    }
}

extern "C" void kernel_launch(void* const* d_in, const int* in_sizes, int n_in,
                              void* d_out, int out_size, void* d_ws, size_t ws_size,
                              hipStream_t stream) {
    const int* X = (const int*)d_in[0];
    const int* Xlen = (const int*)d_in[1];
    const int* sel_b = (const int*)d_in[2];
    const int* sel_t = (const int*)d_in[3];
    const int* eidx = (const int*)d_in[4];
    const float* emb = (const float*)d_in[5];
    const float* w_ih_l0f = (const float*)d_in[6];
    const float* w_hh_l0f = (const float*)d_in[7];
    const float* b_ih_l0f = (const float*)d_in[8];
    const float* b_hh_l0f = (const float*)d_in[9];
    const float* w_ih_l0b = (const float*)d_in[10];
    const float* w_hh_l0b = (const float*)d_in[11];
    const float* b_ih_l0b = (const float*)d_in[12];
    const float* b_hh_l0b = (const float*)d_in[13];
    const float* w_ih_l1f = (const float*)d_in[14];
    const float* w_hh_l1f = (const float*)d_in[15];
    const float* b_ih_l1f = (const float*)d_in[16];
    const float* b_hh_l1f = (const float*)d_in[17];
    const float* w_ih_l1b = (const float*)d_in[18];
    const float* w_hh_l1b = (const float*)d_in[19];
    const float* b_ih_l1b = (const float*)d_in[20];
    const float* b_hh_l1b = (const float*)d_in[21];
    const float* outW = (const float*)d_in[22];
    const float* outb = (const float*)d_in[23];
    const float* expW = (const float*)d_in[24];
    const float* expb = (const float*)d_in[25];

    float* ws = (float*)d_ws;
    float* gates_f = ws;                                   // 13,107,200
    float* gates_b = gates_f + (size_t)TT * BB * GG;       // 13,107,200
    float* hseq1   = gates_b + (size_t)TT * BB * GG;       // 6,553,600 f32
    float* wt0f    = hseq1 + (size_t)BB * TT * 1024;       // 1,048,576
    float* wt0b    = wt0f + (size_t)512 * 2048;
    float* wt1f    = wt0b + (size_t)512 * 2048;
    float* wt1b    = wt1f + (size_t)512 * 2048;
    __hip_bfloat16* hseq0 = (__hip_bfloat16*)(wt1b + (size_t)512 * 2048);  // 6,553,600 bf16
    size_t needed = ((size_t)2 * 13107200 + 6553600 + 4 * 1048576) * 4 + (size_t)6553600 * 2;
    if (ws_size < needed) return;  // diagnostic: absmax would equal max|ref|
    float* out = (float*)d_out;

    whhT_kernel<<<1024, 256, 0, stream>>>(w_hh_l0f, w_hh_l0b, w_hh_l1f, w_hh_l1b,
                                          wt0f, wt0b, wt1f, wt1b);

    dim3 gproj(100, 32);
    xproj_l0_kernel<<<gproj, 256, 0, stream>>>(X, emb, w_ih_l0f, b_ih_l0f, b_hh_l0f, gates_f);
    xproj_l0_kernel<<<gproj, 256, 0, stream>>>(X, emb, w_ih_l0b, b_ih_l0b, b_hh_l0b, gates_b);

    lstm_bp_kernel<0><<<64, 512, 0, stream>>>(gates_f, gates_b, wt0f, wt0b, Xlen, (void*)hseq0);

    xproj_l1_kernel<<<gproj, 256, 0, stream>>>(hseq0, w_ih_l1f, b_ih_l1f, b_hh_l1f, gates_f);
    xproj_l1_kernel<<<gproj, 256, 0, stream>>>(hseq0, w_ih_l1b, b_ih_l1b, b_hh_l1b, gates_b);

    lstm_bp_kernel<1><<<64, 512, 0, stream>>>(gates_f, gates_b, wt1f, wt1b, Xlen, (void*)hseq1);

    ctx_kernel<<<dim3(32, 5), 256, 0, stream>>>(hseq1, outW, outb, sel_b, sel_t, out);
    cls_kernel<<<KSEL, 256, 0, stream>>>(hseq1, expW, expb, sel_b, sel_t, eidx, out);
}

// Round 3
// 4704.747 us; speedup vs baseline: 2.4417x; 2.4417x over previous
//
#include <hip/hip_runtime.h>
#include <hip/hip_bf16.h>

#define BB 64
#define TT 100
#define KSEL 2048
#define EMBD 300
#define EMBP 320
#define HH 512
#define GG 2048   // 4*H
#define NSYN 16

typedef __attribute__((ext_vector_type(8))) _Float16 f16x8;
typedef __attribute__((ext_vector_type(2))) _Float16 f16x2;
typedef __attribute__((ext_vector_type(4))) float f32x4;

__device__ __forceinline__ float dot2f(unsigned int w, unsigned int h, float acc) {
#if __has_builtin(__builtin_amdgcn_fdot2)
    return __builtin_amdgcn_fdot2(__builtin_bit_cast(f16x2, w), __builtin_bit_cast(f16x2, h), acc, false);
#else
    f16x2 wv = __builtin_bit_cast(f16x2, w);
    f16x2 hv = __builtin_bit_cast(f16x2, h);
    return acc + (float)wv[0] * (float)hv[0] + (float)wv[1] * (float)hv[1];
#endif
}

// ---------------- embedding gather -> fp16, padded to 320 cols ----------------
__global__ void embed_kernel(const int* __restrict__ X, const float* __restrict__ emb,
                             _Float16* __restrict__ xemb) {
    int idx = blockIdx.x * blockDim.x + threadIdx.x;
    int total = BB * TT * EMBP;
    if (idx >= total) return;
    int row = idx / EMBP;
    int col = idx - row * EMBP;
    float v = 0.f;
    if (col < EMBD) v = emb[(size_t)X[row] * EMBD + col];
    xemb[idx] = (_Float16)v;
}

// ---------------- W_hh -> fp16 pair-packed transpose ----------------
// WT2[kp*2048 + 4j+q] = pack( W[q*512+j][2kp], W[q*512+j][2kp+1] )
__global__ void wt_prep_kernel(const float* __restrict__ w0f, const float* __restrict__ w0b,
                               const float* __restrict__ w1f, const float* __restrict__ w1b,
                               unsigned int* __restrict__ t0f, unsigned int* __restrict__ t0b,
                               unsigned int* __restrict__ t1f, unsigned int* __restrict__ t1b) {
    __shared__ float tile[64][66];
    int bid = blockIdx.x;
    int arr = bid >> 8;
    int rem = bid & 255;
    int q = rem >> 6;
    int jb = (rem >> 3) & 7;
    int kb = rem & 7;
    const float* W = arr == 0 ? w0f : arr == 1 ? w0b : arr == 2 ? w1f : w1b;
    unsigned int* O = arr == 0 ? t0f : arr == 1 ? t0b : arr == 2 ? t1f : t1b;
    int tid = threadIdx.x;
    {
        int jj = tid >> 2, kl0 = (tid & 3) * 16;
        int pr = q * 512 + jb * 64 + jj;
        for (int c = 0; c < 16; c += 4) {
            float4 v = *(const float4*)(W + (size_t)pr * 512 + kb * 64 + kl0 + c);
            tile[jj][kl0 + c + 0] = v.x;
            tile[jj][kl0 + c + 1] = v.y;
            tile[jj][kl0 + c + 2] = v.z;
            tile[jj][kl0 + c + 3] = v.w;
        }
    }
    __syncthreads();
    {
        int kpl = tid & 31, jj0 = (tid >> 5) * 8;
        for (int i = 0; i < 8; i++) {
            int jj = jj0 + i;
            f16x2 p;
            p[0] = (_Float16)tile[jj][2 * kpl];
            p[1] = (_Float16)tile[jj][2 * kpl + 1];
            O[(size_t)(kb * 32 + kpl) * 2048 + 4 * (jb * 64 + jj) + q] = __builtin_bit_cast(unsigned int, p);
        }
    }
}

// ---------------- MFMA fp16 input projection ----------------
// C[m][n'] = sum_k A[m][k] * W[pr(n')][k],  pr(n') = (n'&3)*512 + (n'>>2)
// A: fp16 [Mrows][Kpad] row-major. mode 0: m = b*100+t -> gates row (t*64+b)
//                                  mode 1: m = t*64+b  -> gates row m
__global__ void __launch_bounds__(256)
xproj_mfma_kernel(const _Float16* __restrict__ A, const float* __restrict__ W,
                  const float* __restrict__ bih, const float* __restrict__ bhh,
                  float* __restrict__ gates, int Kreal, int Kpad, int mode) {
    __shared__ _Float16 A_lds[64][40];
    __shared__ _Float16 B_lds[64][40];
    __shared__ float biasl[64];
    __shared__ int rowb[64];
    int tid = threadIdx.x;
    int m0 = blockIdx.x * 64, n0 = blockIdx.y * 64;
    if (tid < 64) {
        int n = n0 + tid;
        int pr = (n & 3) * 512 + (n >> 2);
        biasl[tid] = bih[pr] + bhh[pr];
        int m = m0 + tid;
        if (mode == 0) {
            int b = m / 100;
            int t = m - b * 100;
            rowb[tid] = (t * 64 + b) * GG;
        } else {
            rowb[tid] = m * GG;
        }
    }
    int w = tid >> 6, l = tid & 63;
    int ml = tid >> 2, kk0 = (tid & 3) * 8;
    f32x4 acc[4] = {};
    __syncthreads();
    for (int k0 = 0; k0 < Kpad; k0 += 32) {
        // stage A (fp16 source, already padded)
        {
            uint4 v = *(const uint4*)(A + (size_t)(m0 + ml) * Kpad + k0 + kk0);
            *(uint4*)&A_lds[ml][kk0] = v;
        }
        // stage B from f32 W rows (permuted), convert to fp16
        {
            int n = n0 + ml;
            int pr = (n & 3) * 512 + (n >> 2);
            const float* src = W + (size_t)pr * Kreal + k0 + kk0;
            if (k0 + 31 < Kreal) {
                float4 v0 = *(const float4*)(src);
                float4 v1 = *(const float4*)(src + 4);
                B_lds[ml][kk0 + 0] = (_Float16)v0.x; B_lds[ml][kk0 + 1] = (_Float16)v0.y;
                B_lds[ml][kk0 + 2] = (_Float16)v0.z; B_lds[ml][kk0 + 3] = (_Float16)v0.w;
                B_lds[ml][kk0 + 4] = (_Float16)v1.x; B_lds[ml][kk0 + 5] = (_Float16)v1.y;
                B_lds[ml][kk0 + 6] = (_Float16)v1.z; B_lds[ml][kk0 + 7] = (_Float16)v1.w;
            } else {
                for (int i = 0; i < 8; i++) {
                    int k = k0 + kk0 + i;
                    B_lds[ml][kk0 + i] = (k < Kreal) ? (_Float16)src[i] : (_Float16)0.f;
                }
            }
        }
        __syncthreads();
        f16x8 bfrag = *(const f16x8*)&B_lds[w * 16 + (l & 15)][(l >> 4) * 8];
#pragma unroll
        for (int mb = 0; mb < 4; mb++) {
            f16x8 afrag = *(const f16x8*)&A_lds[mb * 16 + (l & 15)][(l >> 4) * 8];
            acc[mb] = __builtin_amdgcn_mfma_f32_16x16x32_f16(afrag, bfrag, acc[mb], 0, 0, 0);
        }
        __syncthreads();
    }
#pragma unroll
    for (int mb = 0; mb < 4; mb++) {
#pragma unroll
        for (int r = 0; r < 4; r++) {
            int m_local = mb * 16 + (l >> 4) * 4 + r;
            int n_local = w * 16 + (l & 15);
            gates[(size_t)rowb[m_local] + n0 + n_local] = acc[mb][r] + biasl[n_local];
        }
    }
}

__device__ __forceinline__ float sigf(float x) { return 1.f / (1.f + __expf(-x)); }
__device__ __forceinline__ float tanhfast(float x) {
    float e = __expf(-2.f * fabsf(x));
    float r = (1.f - e) / (1.f + e);
    return copysignf(r, x);
}

// ---------------- batch-parallel bilstm layer, fp16 dot2, no grid sync ----------------
// 32 wgs x 512 threads. XCDs 0-3 fwd, 4-7 bwd. Each wg: 4 whole batches, full dir.
// W fp16 pair-packed [256 kp][2048 n'], 2MB/dir, L2-resident per XCD.
// thread j owns hidden j: gates quad (i,f,g,o) x 4 batches.
template<int MODE>
__global__ void __launch_bounds__(512)
lstm_bp_kernel(const float* __restrict__ gates_f, const float* __restrict__ gates_b,
               const unsigned int* __restrict__ wt_f, const unsigned int* __restrict__ wt_b,
               const int* __restrict__ lengths, void* __restrict__ hseq_out) {
    __shared__ _Float16 hlh[2][256][4][2];   // [buf][kp][batch][parity]
    int bid = blockIdx.x;
    int xcd = bid & 7;
    int dir = xcd >> 2;
    int rank = (bid >> 3) * 4 + (xcd & 3);   // 0..15 within dir
    int b0 = rank * 4;
    int tid = threadIdx.x;                    // j = tid
    const float* g = dir ? gates_b : gates_f;
    const uint4* wrow = (const uint4*)(dir ? wt_b : wt_f) + tid;  // kp stride = 512 uint4
    // zero h buffers
    {
        unsigned int* hz = (unsigned int*)&hlh[0][0][0][0];
        for (int e = tid; e < 2048; e += 512) hz[e] = 0u;
    }
    float c[4] = {0.f, 0.f, 0.f, 0.f};
    float h[4] = {0.f, 0.f, 0.f, 0.f};
    int len[4];
    for (int i = 0; i < 4; i++) len[i] = lengths[b0 + i];
    __syncthreads();
    int cur = 0;
    for (int s = 0; s < TT; s++) {
        int t = dir ? (TT - 1 - s) : s;
        float4 a0 = *(const float4*)(g + ((size_t)(t * 64 + b0 + 0)) * GG + tid * 4);
        float4 a1 = *(const float4*)(g + ((size_t)(t * 64 + b0 + 1)) * GG + tid * 4);
        float4 a2 = *(const float4*)(g + ((size_t)(t * 64 + b0 + 2)) * GG + tid * 4);
        float4 a3 = *(const float4*)(g + ((size_t)(t * 64 + b0 + 3)) * GG + tid * 4);
        float acc[4][4] = {{a0.x, a0.y, a0.z, a0.w}, {a1.x, a1.y, a1.z, a1.w},
                           {a2.x, a2.y, a2.z, a2.w}, {a3.x, a3.y, a3.z, a3.w}};
        const uint4* hbuf = (const uint4*)&hlh[cur][0][0][0];
#pragma unroll 8
        for (int kp = 0; kp < 256; kp++) {
            uint4 w4 = wrow[(size_t)kp * 512];
            uint4 h4 = hbuf[kp];
            unsigned int hh[4] = {h4.x, h4.y, h4.z, h4.w};
            unsigned int ww[4] = {w4.x, w4.y, w4.z, w4.w};
#pragma unroll
            for (int b = 0; b < 4; b++)
#pragma unroll
                for (int q = 0; q < 4; q++)
                    acc[b][q] = dot2f(ww[q], hh[b], acc[b][q]);
        }
#pragma unroll
        for (int b = 0; b < 4; b++) {
            float i_s = sigf(acc[b][0]), f_s = sigf(acc[b][1]);
            float g_t = tanhfast(acc[b][2]), o_s = sigf(acc[b][3]);
            float c_new = f_s * c[b] + i_s * g_t;
            float h_new = o_s * tanhfast(c_new);
            if (t < len[b]) { c[b] = c_new; h[b] = h_new; }
            hlh[cur ^ 1][tid >> 1][b][tid & 1] = (_Float16)h[b];
        }
        if (MODE == 0) {
            _Float16* o = (_Float16*)hseq_out;   // [t*64+b][1024] fp16
            for (int b = 0; b < 4; b++)
                o[((size_t)(t * 64 + b0 + b)) * 1024 + dir * 512 + tid] = (_Float16)h[b];
        } else {
            float* o = (float*)hseq_out;          // [b][t][1024] f32
            for (int b = 0; b < 4; b++)
                o[((size_t)(b0 + b) * TT + t) * 1024 + dir * 512 + tid] = h[b];
        }
        cur ^= 1;
        __syncthreads();
    }
}

// ---------------- ctx = xsel @ out_W^T + out_b ----------------
__global__ void ctx_kernel(const float* __restrict__ hseq1, const float* __restrict__ outW,
                           const float* __restrict__ outb, const int* __restrict__ sel_b,
                           const int* __restrict__ sel_t, float* __restrict__ out) {
    __shared__ float As[16][68];
    __shared__ float Bs[16][68];
    __shared__ int rowbase[64];
    int tid = threadIdx.x;
    int m0 = blockIdx.x * 64, n0 = blockIdx.y * 64;
    if (tid < 64) {
        int m = m0 + tid;
        rowbase[tid] = (sel_b[m] * TT + sel_t[m]) * 1024;
    }
    __syncthreads();
    int tx = tid & 15, ty = tid >> 4;
    float acc[4][4] = {};
    for (int k0 = 0; k0 < 1024; k0 += 16) {
        for (int e = tid; e < 1024; e += 256) {
            int ml = e >> 4, k = e & 15;
            As[k][ml] = hseq1[(size_t)rowbase[ml] + k0 + k];
        }
        for (int e = tid; e < 1024; e += 256) {
            int nl = e >> 4, k = e & 15;
            int n = n0 + nl;
            Bs[k][nl] = (n < EMBD) ? outW[(size_t)n * 1024 + k0 + k] : 0.f;
        }
        __syncthreads();
#pragma unroll
        for (int kk = 0; kk < 16; kk++) {
            float4 a4 = *(const float4*)&As[kk][ty * 4];
            float4 b4 = *(const float4*)&Bs[kk][tx * 4];
            float av[4] = {a4.x, a4.y, a4.z, a4.w};
            float bv[4] = {b4.x, b4.y, b4.z, b4.w};
#pragma unroll
            for (int i = 0; i < 4; i++)
#pragma unroll
                for (int j = 0; j < 4; j++) acc[i][j] += av[i] * bv[j];
        }
        __syncthreads();
    }
    for (int i = 0; i < 4; i++) {
        int m = m0 + ty * 4 + i;
        for (int j = 0; j < 4; j++) {
            int n = n0 + tx * 4 + j;
            if (n < EMBD) out[(size_t)m * EMBD + n] = acc[i][j] + outb[n];
        }
    }
}

// ---------------- cls = einsum('ksd,kd->ks', exp_W[eidx], xsel) + exp_b[eidx] ----------------
__global__ void cls_kernel(const float* __restrict__ hseq1, const float* __restrict__ expW,
                           const float* __restrict__ expb, const int* __restrict__ sel_b,
                           const int* __restrict__ sel_t, const int* __restrict__ eidx,
                           float* __restrict__ out) {
    __shared__ float xr[1024];
    int r = blockIdx.x;
    int tid = threadIdx.x;
    int e = eidx[r];
    int base = (sel_b[r] * TT + sel_t[r]) * 1024;
    for (int q = tid; q < 1024; q += 256) xr[q] = hseq1[(size_t)base + q];
    __syncthreads();
    int lane = tid & 63, wid = tid >> 6;
    for (int p = 0; p < 4; p++) {
        int s = p * 4 + wid;
        const float* wrow = expW + ((size_t)e * NSYN + s) * 1024;
        float partial = 0.f;
#pragma unroll
        for (int i = 0; i < 16; i++) {
            int k = lane + 64 * i;
            partial += xr[k] * wrow[k];
        }
        for (int off = 32; off; off >>= 1) partial += __shfl_down(partial, off);
        if (lane == 0) out[(size_t)KSEL * EMBD + (size_t)r * NSYN + s] = partial + expb[e * NSYN + s];
    }
}

extern "C" void kernel_launch(void* const* d_in, const int* in_sizes, int n_in,
                              void* d_out, int out_size, void* d_ws, size_t ws_size,
                              hipStream_t stream) {
    const int* X = (const int*)d_in[0];
    const int* Xlen = (const int*)d_in[1];
    const int* sel_b = (const int*)d_in[2];
    const int* sel_t = (const int*)d_in[3];
    const int* eidx = (const int*)d_in[4];
    const float* emb = (const float*)d_in[5];
    const float* w_ih_l0f = (const float*)d_in[6];
    const float* w_hh_l0f = (const float*)d_in[7];
    const float* b_ih_l0f = (const float*)d_in[8];
    const float* b_hh_l0f = (const float*)d_in[9];
    const float* w_ih_l0b = (const float*)d_in[10];
    const float* w_hh_l0b = (const float*)d_in[11];
    const float* b_ih_l0b = (const float*)d_in[12];
    const float* b_hh_l0b = (const float*)d_in[13];
    const float* w_ih_l1f = (const float*)d_in[14];
    const float* w_hh_l1f = (const float*)d_in[15];
    const float* b_ih_l1f = (const float*)d_in[16];
    const float* b_hh_l1f = (const float*)d_in[17];
    const float* w_ih_l1b = (const float*)d_in[18];
    const float* w_hh_l1b = (const float*)d_in[19];
    const float* b_ih_l1b = (const float*)d_in[20];
    const float* b_hh_l1b = (const float*)d_in[21];
    const float* outW = (const float*)d_in[22];
    const float* outb = (const float*)d_in[23];
    const float* expW = (const float*)d_in[24];
    const float* expb = (const float*)d_in[25];

    float* ws = (float*)d_ws;
    float* gates_f = ws;                                    // 13,107,200 f32
    float* gates_b = gates_f + (size_t)TT * BB * GG;        // 13,107,200 f32
    float* hseq1   = gates_b + (size_t)TT * BB * GG;        // 6,553,600 f32
    unsigned int* wt0f = (unsigned int*)(hseq1 + (size_t)BB * TT * 1024);  // 524,288 u32 each
    unsigned int* wt0b = wt0f + (size_t)256 * 2048;
    unsigned int* wt1f = wt0b + (size_t)256 * 2048;
    unsigned int* wt1b = wt1f + (size_t)256 * 2048;
    _Float16* hseq0 = (_Float16*)(wt1b + (size_t)256 * 2048);  // 6,553,600 fp16
    _Float16* xemb  = hseq0 + (size_t)6400 * 1024;             // 2,048,000 fp16
    size_t needed = ((size_t)2 * 13107200 + 6553600 + 4 * 524288) * 4
                  + ((size_t)6553600 + 2048000) * 2;
    if (ws_size < needed) return;  // diagnostic: absmax would equal max|ref|
    float* out = (float*)d_out;

    embed_kernel<<<(BB * TT * EMBP + 255) / 256, 256, 0, stream>>>(X, emb, xemb);
    wt_prep_kernel<<<1024, 256, 0, stream>>>(w_hh_l0f, w_hh_l0b, w_hh_l1f, w_hh_l1b,
                                             wt0f, wt0b, wt1f, wt1b);

    dim3 gproj(100, 32);
    xproj_mfma_kernel<<<gproj, 256, 0, stream>>>(xemb, w_ih_l0f, b_ih_l0f, b_hh_l0f, gates_f, EMBD, EMBP, 0);
    xproj_mfma_kernel<<<gproj, 256, 0, stream>>>(xemb, w_ih_l0b, b_ih_l0b, b_hh_l0b, gates_b, EMBD, EMBP, 0);

    lstm_bp_kernel<0><<<32, 512, 0, stream>>>(gates_f, gates_b, wt0f, wt0b, Xlen, (void*)hseq0);

    xproj_mfma_kernel<<<gproj, 256, 0, stream>>>(hseq0, w_ih_l1f, b_ih_l1f, b_hh_l1f, gates_f, 1024, 1024, 1);
    xproj_mfma_kernel<<<gproj, 256, 0, stream>>>(hseq0, w_ih_l1b, b_ih_l1b, b_hh_l1b, gates_b, 1024, 1024, 1);

    lstm_bp_kernel<1><<<32, 512, 0, stream>>>(gates_f, gates_b, wt1f, wt1b, Xlen, (void*)hseq1);

    ctx_kernel<<<dim3(32, 5), 256, 0, stream>>>(hseq1, outW, outb, sel_b, sel_t, out);
    cls_kernel<<<KSEL, 256, 0, stream>>>(hseq1, expW, expb, sel_b, sel_t, eidx, out);
}

// Round 4
// 3628.920 us; speedup vs baseline: 3.1656x; 1.2965x over previous
//
#include <hip/hip_runtime.h>
#include <hip/hip_bf16.h>

#define BB 64
#define TT 100
#define KSEL 2048
#define EMBD 300
#define EMBP 320
#define HH 512
#define GG 2048   // 4*H
#define NSYN 16

typedef __attribute__((ext_vector_type(8))) _Float16 f16x8;
typedef __attribute__((ext_vector_type(4))) float f32x4;

__device__ __forceinline__ float sigf(float x) { return 1.f / (1.f + __expf(-x)); }
__device__ __forceinline__ float tanhfast(float x) {
    float e = __expf(-2.f * fabsf(x));
    float r = (1.f - e) / (1.f + e);
    return copysignf(r, x);
}

// ---------------- embedding gather -> fp16, padded to 320 cols ----------------
__global__ void embed_kernel(const int* __restrict__ X, const float* __restrict__ emb,
                             _Float16* __restrict__ xemb) {
    int idx = blockIdx.x * blockDim.x + threadIdx.x;
    int total = BB * TT * EMBP;
    if (idx >= total) return;
    int row = idx / EMBP;
    int col = idx - row * EMBP;
    float v = 0.f;
    if (col < EMBD) v = emb[(size_t)X[row] * EMBD + col];
    xemb[idx] = (_Float16)v;
}

// ---------------- W_hh -> fp16 permuted-row copy:  W'[n'][k] = W[pr(n')][k] ----------------
// pr(n') = (n'&3)*512 + (n'>>2)   (n' = 4j+q ; rows i,f,g,o interleaved per hidden j)
__global__ void wprep_kernel(const float* __restrict__ w0f, const float* __restrict__ w0b,
                             const float* __restrict__ w1f, const float* __restrict__ w1b,
                             _Float16* __restrict__ o0f, _Float16* __restrict__ o0b,
                             _Float16* __restrict__ o1f, _Float16* __restrict__ o1b) {
    int bid = blockIdx.x;          // 256 blocks
    int mat = bid >> 6;            // 4 matrices
    int rgrp = (bid & 63) * 32;    // 64 blocks x 32 rows = 2048 rows
    const float* W = mat == 0 ? w0f : mat == 1 ? w0b : mat == 2 ? w1f : w1b;
    _Float16* O = mat == 0 ? o0f : mat == 1 ? o0b : mat == 2 ? o1f : o1b;
    int tid = threadIdx.x;
    int rl = tid >> 3;             // 32 rows
    int kc = (tid & 7) * 64;       // 8 chunks of 64
    int np = rgrp + rl;
    int pr = (np & 3) * 512 + (np >> 2);
    const float* src = W + (size_t)pr * 512 + kc;
    _Float16* dst = O + (size_t)np * 512 + kc;
    for (int i = 0; i < 64; i += 4) {
        float4 v = *(const float4*)(src + i);
        dst[i + 0] = (_Float16)v.x;
        dst[i + 1] = (_Float16)v.y;
        dst[i + 2] = (_Float16)v.z;
        dst[i + 3] = (_Float16)v.w;
    }
}

// ---------------- MFMA fp16 input projection (unchanged from R3, passed) ----------------
__global__ void __launch_bounds__(256)
xproj_mfma_kernel(const _Float16* __restrict__ A, const float* __restrict__ W,
                  const float* __restrict__ bih, const float* __restrict__ bhh,
                  float* __restrict__ gates, int Kreal, int Kpad, int mode) {
    __shared__ _Float16 A_lds[64][40];
    __shared__ _Float16 B_lds[64][40];
    __shared__ float biasl[64];
    __shared__ int rowb[64];
    int tid = threadIdx.x;
    int m0 = blockIdx.x * 64, n0 = blockIdx.y * 64;
    if (tid < 64) {
        int n = n0 + tid;
        int pr = (n & 3) * 512 + (n >> 2);
        biasl[tid] = bih[pr] + bhh[pr];
        int m = m0 + tid;
        if (mode == 0) {
            int b = m / 100;
            int t = m - b * 100;
            rowb[tid] = (t * 64 + b) * GG;
        } else {
            rowb[tid] = m * GG;
        }
    }
    int w = tid >> 6, l = tid & 63;
    int ml = tid >> 2, kk0 = (tid & 3) * 8;
    f32x4 acc[4] = {};
    __syncthreads();
    for (int k0 = 0; k0 < Kpad; k0 += 32) {
        {
            uint4 v = *(const uint4*)(A + (size_t)(m0 + ml) * Kpad + k0 + kk0);
            *(uint4*)&A_lds[ml][kk0] = v;
        }
        {
            int n = n0 + ml;
            int pr = (n & 3) * 512 + (n >> 2);
            const float* src = W + (size_t)pr * Kreal + k0 + kk0;
            if (k0 + 31 < Kreal) {
                float4 v0 = *(const float4*)(src);
                float4 v1 = *(const float4*)(src + 4);
                B_lds[ml][kk0 + 0] = (_Float16)v0.x; B_lds[ml][kk0 + 1] = (_Float16)v0.y;
                B_lds[ml][kk0 + 2] = (_Float16)v0.z; B_lds[ml][kk0 + 3] = (_Float16)v0.w;
                B_lds[ml][kk0 + 4] = (_Float16)v1.x; B_lds[ml][kk0 + 5] = (_Float16)v1.y;
                B_lds[ml][kk0 + 6] = (_Float16)v1.z; B_lds[ml][kk0 + 7] = (_Float16)v1.w;
            } else {
                for (int i = 0; i < 8; i++) {
                    int k = k0 + kk0 + i;
                    B_lds[ml][kk0 + i] = (k < Kreal) ? (_Float16)src[i] : (_Float16)0.f;
                }
            }
        }
        __syncthreads();
        f16x8 bfrag = *(const f16x8*)&B_lds[w * 16 + (l & 15)][(l >> 4) * 8];
#pragma unroll
        for (int mb = 0; mb < 4; mb++) {
            f16x8 afrag = *(const f16x8*)&A_lds[mb * 16 + (l & 15)][(l >> 4) * 8];
            acc[mb] = __builtin_amdgcn_mfma_f32_16x16x32_f16(afrag, bfrag, acc[mb], 0, 0, 0);
        }
        __syncthreads();
    }
#pragma unroll
    for (int mb = 0; mb < 4; mb++) {
#pragma unroll
        for (int r = 0; r < 4; r++) {
            int m_local = mb * 16 + (l >> 4) * 4 + r;
            int n_local = w * 16 + (l & 15);
            gates[(size_t)rowb[m_local] + n0 + n_local] = acc[mb][r] + biasl[n_local];
        }
    }
}

// ---------------- j-split bilstm layer: register-resident W, flag exchange ----------------
// 64 wgs x 512 thr (cooperative). dir = bid&1, cu = bid>>1 (32 CUs/dir).
// CU owns n' columns [cu*64, cu*64+64) = 16 hidden j, for ALL 64 batches.
// W-slice: 16 B-fragments (f16x8) per wave = 64 VGPRs, loaded once.
// Exchange: h(t) rows of hs[(t*64+b)*1024 + dir*512 + j]; per-CU flag = steps done.
__global__ void __launch_bounds__(512, 1)
lstm_sync_kernel(const float* __restrict__ gf, const float* __restrict__ gb,
                 const _Float16* __restrict__ wpf, const _Float16* __restrict__ wpb,
                 const int* __restrict__ lengths, _Float16* __restrict__ hs,
                 unsigned* __restrict__ flags) {
    __shared__ uint4 hlds[4096];   // 64KB: h staged [b][k] fp16, granule-swizzled
    int bid = blockIdx.x;
    int dir = bid & 1;
    int cu = bid >> 1;             // 0..31
    int n0 = cu * 64;
    const float* g = dir ? gb : gf;
    const _Float16* wp = dir ? wpb : wpf;
    unsigned* myflags = flags + dir * 32 * 16;
    int tid = threadIdx.x;
    int w = tid >> 6, l = tid & 63;
    int nt = w & 3, mh = w >> 2;       // n-tile (0..3), m-half (0..1)
    int lc = l & 15, lk = l >> 4;      // in-tile col, k/row-chunk
    int jq = n0 + nt * 16 + lc;        // this lane's n'
    int q = jq & 3, j = jq >> 2;       // gate id, hidden id

    // ---- preload B fragments (W-slice) into registers, once ----
    f16x8 breg[16];
    const _Float16* wrow = wp + (size_t)jq * 512 + lk * 8;
#pragma unroll
    for (int ks = 0; ks < 16; ks++) breg[ks] = *(const f16x8*)(wrow + ks * 32);

    // ---- per-lane state: 8 (b, j) pairs (acc/D layout rows) ----
    float cst[8];
    float hst[8];
    int lenv[8];
#pragma unroll
    for (int mi = 0; mi < 2; mi++)
#pragma unroll
        for (int r = 0; r < 4; r++) {
            int idx = mi * 4 + r;
            int b = mh * 32 + mi * 16 + lk * 4 + r;
            lenv[idx] = lengths[b];
            cst[idx] = 0.f; hst[idx] = 0.f;
        }

    for (int s = 0; s < TT; s++) {
        int t = dir ? (TT - 1 - s) : s;
        // gate-init loads (independent of flags; issued before poll)
        f32x4 acc[2];
#pragma unroll
        for (int mi = 0; mi < 2; mi++)
#pragma unroll
            for (int r = 0; r < 4; r++) {
                int b = mh * 32 + mi * 16 + lk * 4 + r;
                acc[mi][r] = g[((size_t)(t * 64 + b)) * GG + jq];
            }
        if (s > 0) {
            int tp = dir ? (t + 1) : (t - 1);
            // ---- poll producer flags (all 32 CUs of this dir >= s) ----
            unsigned tgt = (unsigned)s;
            int fi = (l & 31) * 16;
            while (true) {
                unsigned v = __hip_atomic_load(myflags + fi, __ATOMIC_RELAXED,
                                               __HIP_MEMORY_SCOPE_AGENT);
                if (__all(v >= tgt)) break;
            }
            __threadfence();   // acquire: make producers' h stores visible
            // ---- stage h(tp) -> LDS, granule-XOR swizzle ----
            const _Float16* hrow = hs + (size_t)(tp * 64) * 1024 + dir * 512;
#pragma unroll
            for (int i = 0; i < 8; i++) {
                int gx = i * 512 + tid;
                int b = gx >> 6, ci = gx & 63;
                uint4 v = *(const uint4*)(hrow + (size_t)b * 1024 + ci * 8);
                hlds[(b << 6) | (ci ^ (b & 7))] = v;
            }
            __syncthreads();
            // ---- MFMA: acc[mi] += h-tile x W-slice ----
#pragma unroll
            for (int mi = 0; mi < 2; mi++) {
                int ba = mh * 32 + mi * 16 + lc;   // A-frag row (batch)
#pragma unroll
                for (int ks = 0; ks < 16; ks++) {
                    int ci = ks * 4 + lk;
                    f16x8 af = *(const f16x8*)((const char*)hlds +
                                 (((ba << 6) | (ci ^ (ba & 7))) << 4));
                    acc[mi] = __builtin_amdgcn_mfma_f32_16x16x32_f16(af, breg[ks], acc[mi], 0, 0, 0);
                }
            }
        }
        // ---- epilogue: activations + state update (4-lane gate transpose) ----
#pragma unroll
        for (int mi = 0; mi < 2; mi++)
#pragma unroll
            for (int r = 0; r < 4; r++) {
                int idx = mi * 4 + r;
                float pre = acc[mi][r];
                float sg = sigf(pre), th = tanhfast(pre);
                float a = (q == 2) ? th : sg;
                float p1 = __shfl_xor(a, 1);
                float p2 = __shfl_xor(a, 2);
                float p3 = __shfl_xor(p1, 2);
                float gi = q == 0 ? a : q == 1 ? p1 : q == 2 ? p2 : p3;
                float gfv = q == 0 ? p1 : q == 1 ? a : q == 2 ? p3 : p2;
                float gg = q == 0 ? p2 : q == 1 ? p3 : q == 2 ? a : p1;
                float go = q == 0 ? p3 : q == 1 ? p2 : q == 2 ? p1 : a;
                float cn = gfv * cst[idx] + gi * gg;
                float hn = go * tanhfast(cn);
                if (t < lenv[idx]) { cst[idx] = cn; hst[idx] = hn; }
            }
        // ---- publish h(t): q==0 lanes write [b][j] fp16 ----
        if (q == 0) {
#pragma unroll
            for (int mi = 0; mi < 2; mi++)
#pragma unroll
                for (int r = 0; r < 4; r++) {
                    int idx = mi * 4 + r;
                    int b = mh * 32 + mi * 16 + lk * 4 + r;
                    hs[((size_t)(t * 64 + b)) * 1024 + dir * 512 + j] = (_Float16)hst[idx];
                }
        }
        __syncthreads();   // drains all waves' stores (vmcnt before barrier)
        if (tid == 0)
            __hip_atomic_store(myflags + cu * 16, (unsigned)(s + 1),
                               __ATOMIC_RELEASE, __HIP_MEMORY_SCOPE_AGENT);
    }
}

// ---------------- ctx = xsel @ out_W^T + out_b  (xsel from fp16 hs1) ----------------
__global__ void ctx_kernel(const _Float16* __restrict__ hs1, const float* __restrict__ outW,
                           const float* __restrict__ outb, const int* __restrict__ sel_b,
                           const int* __restrict__ sel_t, float* __restrict__ out) {
    __shared__ float As[16][68];
    __shared__ float Bs[16][68];
    __shared__ int rowbase[64];
    int tid = threadIdx.x;
    int m0 = blockIdx.x * 64, n0 = blockIdx.y * 64;
    if (tid < 64) {
        int m = m0 + tid;
        rowbase[tid] = (sel_t[m] * 64 + sel_b[m]) * 1024;
    }
    __syncthreads();
    int tx = tid & 15, ty = tid >> 4;
    float acc[4][4] = {};
    for (int k0 = 0; k0 < 1024; k0 += 16) {
        for (int e = tid; e < 1024; e += 256) {
            int ml = e >> 4, k = e & 15;
            As[k][ml] = (float)hs1[(size_t)rowbase[ml] + k0 + k];
        }
        for (int e = tid; e < 1024; e += 256) {
            int nl = e >> 4, k = e & 15;
            int n = n0 + nl;
            Bs[k][nl] = (n < EMBD) ? outW[(size_t)n * 1024 + k0 + k] : 0.f;
        }
        __syncthreads();
#pragma unroll
        for (int kk = 0; kk < 16; kk++) {
            float4 a4 = *(const float4*)&As[kk][ty * 4];
            float4 b4 = *(const float4*)&Bs[kk][tx * 4];
            float av[4] = {a4.x, a4.y, a4.z, a4.w};
            float bv[4] = {b4.x, b4.y, b4.z, b4.w};
#pragma unroll
            for (int i = 0; i < 4; i++)
#pragma unroll
                for (int jj = 0; jj < 4; jj++) acc[i][jj] += av[i] * bv[jj];
        }
        __syncthreads();
    }
    for (int i = 0; i < 4; i++) {
        int m = m0 + ty * 4 + i;
        for (int jj = 0; jj < 4; jj++) {
            int n = n0 + tx * 4 + jj;
            if (n < EMBD) out[(size_t)m * EMBD + n] = acc[i][jj] + outb[n];
        }
    }
}

// ---------------- cls = einsum('ksd,kd->ks', exp_W[eidx], xsel) + exp_b[eidx] ----------------
__global__ void cls_kernel(const _Float16* __restrict__ hs1, const float* __restrict__ expW,
                           const float* __restrict__ expb, const int* __restrict__ sel_b,
                           const int* __restrict__ sel_t, const int* __restrict__ eidx,
                           float* __restrict__ out) {
    __shared__ float xr[1024];
    int r = blockIdx.x;
    int tid = threadIdx.x;
    int e = eidx[r];
    int base = (sel_t[r] * 64 + sel_b[r]) * 1024;
    for (int qq = tid; qq < 1024; qq += 256) xr[qq] = (float)hs1[(size_t)base + qq];
    __syncthreads();
    int lane = tid & 63, wid = tid >> 6;
    for (int p = 0; p < 4; p++) {
        int s = p * 4 + wid;
        const float* wrow = expW + ((size_t)e * NSYN + s) * 1024;
        float partial = 0.f;
#pragma unroll
        for (int i = 0; i < 16; i++) {
            int k = lane + 64 * i;
            partial += xr[k] * wrow[k];
        }
        for (int off = 32; off; off >>= 1) partial += __shfl_down(partial, off);
        if (lane == 0) out[(size_t)KSEL * EMBD + (size_t)r * NSYN + s] = partial + expb[e * NSYN + s];
    }
}

extern "C" void kernel_launch(void* const* d_in, const int* in_sizes, int n_in,
                              void* d_out, int out_size, void* d_ws, size_t ws_size,
                              hipStream_t stream) {
    const int* X = (const int*)d_in[0];
    const int* Xlen = (const int*)d_in[1];
    const int* sel_b = (const int*)d_in[2];
    const int* sel_t = (const int*)d_in[3];
    const int* eidx = (const int*)d_in[4];
    const float* emb = (const float*)d_in[5];
    const float* w_ih_l0f = (const float*)d_in[6];
    const float* w_hh_l0f = (const float*)d_in[7];
    const float* b_ih_l0f = (const float*)d_in[8];
    const float* b_hh_l0f = (const float*)d_in[9];
    const float* w_ih_l0b = (const float*)d_in[10];
    const float* w_hh_l0b = (const float*)d_in[11];
    const float* b_ih_l0b = (const float*)d_in[12];
    const float* b_hh_l0b = (const float*)d_in[13];
    const float* w_ih_l1f = (const float*)d_in[14];
    const float* w_hh_l1f = (const float*)d_in[15];
    const float* b_ih_l1f = (const float*)d_in[16];
    const float* b_hh_l1f = (const float*)d_in[17];
    const float* w_ih_l1b = (const float*)d_in[18];
    const float* w_hh_l1b = (const float*)d_in[19];
    const float* b_ih_l1b = (const float*)d_in[20];
    const float* b_hh_l1b = (const float*)d_in[21];
    const float* outW = (const float*)d_in[22];
    const float* outb = (const float*)d_in[23];
    const float* expW = (const float*)d_in[24];
    const float* expb = (const float*)d_in[25];

    char* ws = (char*)d_ws;
    float* gates_f = (float*)ws;                                  // 52,428,800 B
    float* gates_b = (float*)(ws + 52428800);                     // 52,428,800 B
    _Float16* wp0f = (_Float16*)(ws + 104857600);                 // 2,097,152 B each
    _Float16* wp0b = (_Float16*)(ws + 106954752);
    _Float16* wp1f = (_Float16*)(ws + 109051904);
    _Float16* wp1b = (_Float16*)(ws + 111149056);
    _Float16* hs0  = (_Float16*)(ws + 113246208);                 // 13,107,200 B
    _Float16* hs1  = (_Float16*)(ws + 126353408);                 // 13,107,200 B
    _Float16* xemb = (_Float16*)(ws + 139460608);                 // 4,096,000 B
    unsigned* flags0 = (unsigned*)(ws + 143556608);               // 4,096 B
    unsigned* flags1 = (unsigned*)(ws + 143560704);               // 4,096 B
    size_t needed = 143564800;
    if (ws_size < needed) return;  // diagnostic: absmax would equal max|ref|
    float* out = (float*)d_out;

    hipMemsetAsync(flags0, 0, 8192, stream);   // zero both layers' flag sets

    embed_kernel<<<(BB * TT * EMBP + 255) / 256, 256, 0, stream>>>(X, emb, xemb);
    wprep_kernel<<<256, 256, 0, stream>>>(w_hh_l0f, w_hh_l0b, w_hh_l1f, w_hh_l1b,
                                          wp0f, wp0b, wp1f, wp1b);

    dim3 gproj(100, 32);
    xproj_mfma_kernel<<<gproj, 256, 0, stream>>>(xemb, w_ih_l0f, b_ih_l0f, b_hh_l0f, gates_f, EMBD, EMBP, 0);
    xproj_mfma_kernel<<<gproj, 256, 0, stream>>>(xemb, w_ih_l0b, b_ih_l0b, b_hh_l0b, gates_b, EMBD, EMBP, 0);

    {
        const float* a0 = gates_f; const float* a1 = gates_b;
        const _Float16* a2 = wp0f; const _Float16* a3 = wp0b;
        const int* a4 = Xlen; _Float16* a5 = hs0; unsigned* a6 = flags0;
        void* args[] = {(void*)&a0, (void*)&a1, (void*)&a2, (void*)&a3,
                        (void*)&a4, (void*)&a5, (void*)&a6};
        hipLaunchCooperativeKernel((const void*)lstm_sync_kernel, dim3(64), dim3(512), args, 0, stream);
    }

    xproj_mfma_kernel<<<gproj, 256, 0, stream>>>(hs0, w_ih_l1f, b_ih_l1f, b_hh_l1f, gates_f, 1024, 1024, 1);
    xproj_mfma_kernel<<<gproj, 256, 0, stream>>>(hs0, w_ih_l1b, b_ih_l1b, b_hh_l1b, gates_b, 1024, 1024, 1);

    {
        const float* a0 = gates_f; const float* a1 = gates_b;
        const _Float16* a2 = wp1f; const _Float16* a3 = wp1b;
        const int* a4 = Xlen; _Float16* a5 = hs1; unsigned* a6 = flags1;
        void* args[] = {(void*)&a0, (void*)&a1, (void*)&a2, (void*)&a3,
                        (void*)&a4, (void*)&a5, (void*)&a6};
        hipLaunchCooperativeKernel((const void*)lstm_sync_kernel, dim3(64), dim3(512), args, 0, stream);
    }

    ctx_kernel<<<dim3(32, 5), 256, 0, stream>>>(hs1, outW, outb, sel_b, sel_t, out);
    cls_kernel<<<KSEL, 256, 0, stream>>>(hs1, expW, expb, sel_b, sel_t, eidx, out);
}

// Round 5
// 3145.161 us; speedup vs baseline: 3.6525x; 1.1538x over previous
//
#include <hip/hip_runtime.h>
#include <hip/hip_bf16.h>

#define BB 64
#define TT 100
#define KSEL 2048
#define EMBD 300
#define EMBP 320
#define HH 512
#define GG 2048   // 4*H
#define NSYN 16

typedef __attribute__((ext_vector_type(8))) _Float16 f16x8;
typedef __attribute__((ext_vector_type(4))) float f32x4;

__device__ __forceinline__ float sigf(float x) { return 1.f / (1.f + __expf(-x)); }
__device__ __forceinline__ float tanhfast(float x) {
    float e = __expf(-2.f * fabsf(x));
    float r = (1.f - e) / (1.f + e);
    return copysignf(r, x);
}

// ---------------- embedding gather -> fp16, rows in (t*64+b) order ----------------
__global__ void embed_kernel(const int* __restrict__ X, const float* __restrict__ emb,
                             _Float16* __restrict__ xemb) {
    int idx = blockIdx.x * blockDim.x + threadIdx.x;
    int total = BB * TT * EMBP;
    if (idx >= total) return;
    int row = idx / EMBP;
    int col = idx - row * EMBP;
    int b = row & 63, t = row >> 6;
    float v = 0.f;
    if (col < EMBD) v = emb[(size_t)X[b * TT + t] * EMBD + col];
    xemb[idx] = (_Float16)v;
}

// ---------------- W_hh -> fp16 permuted-row copy:  W'[n'][k] = W[pr(n')][k] ----------------
// pr(n') = (n'&3)*512 + (n'>>2)
__global__ void wprep_kernel(const float* __restrict__ w0f, const float* __restrict__ w0b,
                             const float* __restrict__ w1f, const float* __restrict__ w1b,
                             _Float16* __restrict__ o0f, _Float16* __restrict__ o0b,
                             _Float16* __restrict__ o1f, _Float16* __restrict__ o1b) {
    int bid = blockIdx.x;          // 256 blocks
    int mat = bid >> 6;
    int rgrp = (bid & 63) * 32;
    const float* W = mat == 0 ? w0f : mat == 1 ? w0b : mat == 2 ? w1f : w1b;
    _Float16* O = mat == 0 ? o0f : mat == 1 ? o0b : mat == 2 ? o1f : o1b;
    int tid = threadIdx.x;
    int rl = tid >> 3;
    int kc = (tid & 7) * 64;
    int np = rgrp + rl;
    int pr = (np & 3) * 512 + (np >> 2);
    const float* src = W + (size_t)pr * 512 + kc;
    _Float16* dst = O + (size_t)np * 512 + kc;
    for (int i = 0; i < 64; i += 4) {
        float4 v = *(const float4*)(src + i);
        dst[i + 0] = (_Float16)v.x;
        dst[i + 1] = (_Float16)v.y;
        dst[i + 2] = (_Float16)v.z;
        dst[i + 3] = (_Float16)v.w;
    }
}

// ---------------- MFMA fp16 input projection, output transposed gatesT[t][n'][b] ----------------
// A fp16 [6400][Kpad], rows m = t*64+b. blockIdx.x = t, blockIdx.y = n-tile.
__global__ void __launch_bounds__(256)
xproj_mfma_kernel(const _Float16* __restrict__ A, const float* __restrict__ W,
                  const float* __restrict__ bih, const float* __restrict__ bhh,
                  float* __restrict__ gatesT, int Kreal, int Kpad) {
    __shared__ _Float16 A_lds[64][40];
    __shared__ _Float16 B_lds[64][40];
    __shared__ float biasl[64];
    int tid = threadIdx.x;
    int t = blockIdx.x;
    int m0 = t * 64, n0 = blockIdx.y * 64;
    if (tid < 64) {
        int n = n0 + tid;
        int pr = (n & 3) * 512 + (n >> 2);
        biasl[tid] = bih[pr] + bhh[pr];
    }
    int w = tid >> 6, l = tid & 63;
    int ml = tid >> 2, kk0 = (tid & 3) * 8;
    f32x4 acc[4] = {};
    __syncthreads();
    for (int k0 = 0; k0 < Kpad; k0 += 32) {
        {
            uint4 v = *(const uint4*)(A + (size_t)(m0 + ml) * Kpad + k0 + kk0);
            *(uint4*)&A_lds[ml][kk0] = v;
        }
        {
            int n = n0 + ml;
            int pr = (n & 3) * 512 + (n >> 2);
            const float* src = W + (size_t)pr * Kreal + k0 + kk0;
            if (k0 + 31 < Kreal) {
                float4 v0 = *(const float4*)(src);
                float4 v1 = *(const float4*)(src + 4);
                B_lds[ml][kk0 + 0] = (_Float16)v0.x; B_lds[ml][kk0 + 1] = (_Float16)v0.y;
                B_lds[ml][kk0 + 2] = (_Float16)v0.z; B_lds[ml][kk0 + 3] = (_Float16)v0.w;
                B_lds[ml][kk0 + 4] = (_Float16)v1.x; B_lds[ml][kk0 + 5] = (_Float16)v1.y;
                B_lds[ml][kk0 + 6] = (_Float16)v1.z; B_lds[ml][kk0 + 7] = (_Float16)v1.w;
            } else {
                for (int i = 0; i < 8; i++) {
                    int k = k0 + kk0 + i;
                    B_lds[ml][kk0 + i] = (k < Kreal) ? (_Float16)src[i] : (_Float16)0.f;
                }
            }
        }
        __syncthreads();
        f16x8 bfrag = *(const f16x8*)&B_lds[w * 16 + (l & 15)][(l >> 4) * 8];
#pragma unroll
        for (int mb = 0; mb < 4; mb++) {
            f16x8 afrag = *(const f16x8*)&A_lds[mb * 16 + (l & 15)][(l >> 4) * 8];
            acc[mb] = __builtin_amdgcn_mfma_f32_16x16x32_f16(afrag, bfrag, acc[mb], 0, 0, 0);
        }
        __syncthreads();
    }
    int n_local = w * 16 + (l & 15);
    float bias = biasl[n_local];
#pragma unroll
    for (int mb = 0; mb < 4; mb++) {
        float4 st;
        st.x = acc[mb][0] + bias;
        st.y = acc[mb][1] + bias;
        st.z = acc[mb][2] + bias;
        st.w = acc[mb][3] + bias;
        *(float4*)&gatesT[((size_t)t * 2048 + n0 + n_local) * 64 + mb * 16 + (l >> 4) * 4] = st;
    }
}

// ---------------- bilstm layer: 8 XCD-local groups (2 dir x 4 batch-groups) ----------------
// 64 wgs x 512 thr (cooperative). group g = bid&7 (one XCD if round-robin), member = bid>>3.
// Group: dir = g&1, batches [bg*16, bg*16+16). Member owns n' [mem*256, +256) with W-slice
// register-resident (breg[2][16] f16x8 = 128 VGPR). Exchange: 16KB h per step via hs +
// per-member flags (agent release/acquire), all within the group's XCD L2.
__global__ void __launch_bounds__(512, 2)
lstm_group_kernel(const float* __restrict__ gTf, const float* __restrict__ gTb,
                  const _Float16* __restrict__ wpf, const _Float16* __restrict__ wpb,
                  const int* __restrict__ lengths, _Float16* __restrict__ hs,
                  unsigned* __restrict__ flags) {
    __shared__ uint4 hlds[1024];            // 16KB staged h(t-1): [16 b][512 j] fp16, XOR-swizzled
    __shared__ _Float16 hpack[16][64];      // 2KB publish repack
    int bid = blockIdx.x;
    int g = bid & 7, mem = bid >> 3;
    int dir = g & 1, bg = g >> 1;
    const float* gT = dir ? gTb : gTf;
    const _Float16* wp = dir ? wpb : wpf;
    unsigned* gflags = flags + g * 128;     // 8 members x 16-u32 pad
    int tid = threadIdx.x;
    int w = tid >> 6, l = tid & 63;
    int lc = l & 15, hi = l >> 4;
    int q = lc & 3;
    int nbase = mem * 256 + w * 32;

    // ---- preload W-slice into registers (once) ----
    f16x8 breg[2][16];
#pragma unroll
    for (int nt = 0; nt < 2; nt++) {
        const _Float16* src = wp + (size_t)(nbase + nt * 16 + lc) * 512 + hi * 8;
#pragma unroll
        for (int ks = 0; ks < 16; ks++)
            breg[nt][ks] = *(const f16x8*)(src + ks * 32);
    }
    float cst[2][4] = {};
    float hst[2][4] = {};
    int lenv[4];
#pragma unroll
    for (int r = 0; r < 4; r++) lenv[r] = lengths[bg * 16 + hi * 4 + r];
    int jj[2];
#pragma unroll
    for (int nt = 0; nt < 2; nt++) jj[nt] = (nbase + nt * 16 + lc) >> 2;

    for (int s = 0; s < TT; s++) {
        int t = dir ? (TT - 1 - s) : s;
        // gate init (issued before poll; overlaps wait)
        f32x4 acc[2];
#pragma unroll
        for (int nt = 0; nt < 2; nt++) {
            const float* src = gT + ((size_t)t * 2048 + nbase + nt * 16 + lc) * 64 + bg * 16 + hi * 4;
            float4 v = *(const float4*)src;
            acc[nt][0] = v.x; acc[nt][1] = v.y; acc[nt][2] = v.z; acc[nt][3] = v.w;
        }
        if (s > 0) {
            int tp = dir ? (t + 1) : (t - 1);
            // poll all 8 member flags >= s
            unsigned tgt = (unsigned)s;
            int fi = (l & 7) * 16;
            while (true) {
                unsigned v = __hip_atomic_load(gflags + fi, __ATOMIC_RELAXED,
                                               __HIP_MEMORY_SCOPE_AGENT);
                if (__all(v >= tgt)) break;
            }
            __threadfence();   // acquire
            // stage h(t-1) of our 16 batches -> LDS, 16B-granule XOR swizzle
            const _Float16* hrow = hs + ((size_t)(tp * 64 + bg * 16)) * 1024 + dir * 512;
#pragma unroll
            for (int i = 0; i < 2; i++) {
                int idx = i * 512 + tid;
                int b = idx >> 6, gi = idx & 63;
                uint4 v = *(const uint4*)(hrow + (size_t)b * 1024 + gi * 8);
                hlds[(b << 6) | (gi ^ (b & 7))] = v;
            }
            __syncthreads();
#pragma unroll
            for (int ks = 0; ks < 16; ks++) {
                f16x8 af = *(const f16x8*)((const char*)hlds +
                             (((lc << 6) | ((ks * 4 + hi) ^ (lc & 7))) << 4));
                acc[0] = __builtin_amdgcn_mfma_f32_16x16x32_f16(af, breg[0][ks], acc[0], 0, 0, 0);
                acc[1] = __builtin_amdgcn_mfma_f32_16x16x32_f16(af, breg[1][ks], acc[1], 0, 0, 0);
            }
        }
        // epilogue: 4-lane gate transpose + state update
#pragma unroll
        for (int nt = 0; nt < 2; nt++)
#pragma unroll
            for (int r = 0; r < 4; r++) {
                float pre = acc[nt][r];
                float sg = sigf(pre), th = tanhfast(pre);
                float a = (q == 2) ? th : sg;
                float p1 = __shfl_xor(a, 1);
                float p2 = __shfl_xor(a, 2);
                float p3 = __shfl_xor(p1, 2);
                float gi_ = q == 0 ? a : q == 1 ? p1 : q == 2 ? p2 : p3;
                float gf_ = q == 0 ? p1 : q == 1 ? a : q == 2 ? p3 : p2;
                float gg_ = q == 0 ? p2 : q == 1 ? p3 : q == 2 ? a : p1;
                float go_ = q == 0 ? p3 : q == 1 ? p2 : q == 2 ? p1 : a;
                float cn = gf_ * cst[nt][r] + gi_ * gg_;
                float hn = go_ * tanhfast(cn);
                if (t < lenv[r]) { cst[nt][r] = cn; hst[nt][r] = hn; }
                if (q == 0) hpack[hi * 4 + r][w * 8 + nt * 4 + (lc >> 2)] = (_Float16)hst[nt][r];
            }
        __syncthreads();
        // coalesced publish: 512 threads x u32 (2 fp16)
        {
            int b = tid >> 5, jp = tid & 31;
            unsigned v = *(const unsigned*)&hpack[b][jp * 2];
            *(unsigned*)(hs + ((size_t)(t * 64 + bg * 16 + b)) * 1024 + dir * 512 + mem * 64 + jp * 2) = v;
        }
        __syncthreads();   // drains stores (vmcnt) across all waves
        if (tid == 0)
            __hip_atomic_store(gflags + mem * 16, (unsigned)(s + 1),
                               __ATOMIC_RELEASE, __HIP_MEMORY_SCOPE_AGENT);
    }
}

// ---------------- ctx = xsel @ out_W^T + out_b ----------------
__global__ void ctx_kernel(const _Float16* __restrict__ hs1, const float* __restrict__ outW,
                           const float* __restrict__ outb, const int* __restrict__ sel_b,
                           const int* __restrict__ sel_t, float* __restrict__ out) {
    __shared__ float As[16][68];
    __shared__ float Bs[16][68];
    __shared__ int rowbase[64];
    int tid = threadIdx.x;
    int m0 = blockIdx.x * 64, n0 = blockIdx.y * 64;
    if (tid < 64) {
        int m = m0 + tid;
        rowbase[tid] = (sel_t[m] * 64 + sel_b[m]) * 1024;
    }
    __syncthreads();
    int tx = tid & 15, ty = tid >> 4;
    float acc[4][4] = {};
    for (int k0 = 0; k0 < 1024; k0 += 16) {
        for (int e = tid; e < 1024; e += 256) {
            int ml = e >> 4, k = e & 15;
            As[k][ml] = (float)hs1[(size_t)rowbase[ml] + k0 + k];
        }
        for (int e = tid; e < 1024; e += 256) {
            int nl = e >> 4, k = e & 15;
            int n = n0 + nl;
            Bs[k][nl] = (n < EMBD) ? outW[(size_t)n * 1024 + k0 + k] : 0.f;
        }
        __syncthreads();
#pragma unroll
        for (int kk = 0; kk < 16; kk++) {
            float4 a4 = *(const float4*)&As[kk][ty * 4];
            float4 b4 = *(const float4*)&Bs[kk][tx * 4];
            float av[4] = {a4.x, a4.y, a4.z, a4.w};
            float bv[4] = {b4.x, b4.y, b4.z, b4.w};
#pragma unroll
            for (int i = 0; i < 4; i++)
#pragma unroll
                for (int jj = 0; jj < 4; jj++) acc[i][jj] += av[i] * bv[jj];
        }
        __syncthreads();
    }
    for (int i = 0; i < 4; i++) {
        int m = m0 + ty * 4 + i;
        for (int jj = 0; jj < 4; jj++) {
            int n = n0 + tx * 4 + jj;
            if (n < EMBD) out[(size_t)m * EMBD + n] = acc[i][jj] + outb[n];
        }
    }
}

// ---------------- cls = einsum('ksd,kd->ks', exp_W[eidx], xsel) + exp_b[eidx] ----------------
__global__ void cls_kernel(const _Float16* __restrict__ hs1, const float* __restrict__ expW,
                           const float* __restrict__ expb, const int* __restrict__ sel_b,
                           const int* __restrict__ sel_t, const int* __restrict__ eidx,
                           float* __restrict__ out) {
    __shared__ float xr[1024];
    int r = blockIdx.x;
    int tid = threadIdx.x;
    int e = eidx[r];
    int base = (sel_t[r] * 64 + sel_b[r]) * 1024;
    for (int qq = tid; qq < 1024; qq += 256) xr[qq] = (float)hs1[(size_t)base + qq];
    __syncthreads();
    int lane = tid & 63, wid = tid >> 6;
    for (int p = 0; p < 4; p++) {
        int s = p * 4 + wid;
        const float* wrow = expW + ((size_t)e * NSYN + s) * 1024;
        float partial = 0.f;
#pragma unroll
        for (int i = 0; i < 16; i++) {
            int k = lane + 64 * i;
            partial += xr[k] * wrow[k];
        }
        for (int off = 32; off; off >>= 1) partial += __shfl_down(partial, off);
        if (lane == 0) out[(size_t)KSEL * EMBD + (size_t)r * NSYN + s] = partial + expb[e * NSYN + s];
    }
}

extern "C" void kernel_launch(void* const* d_in, const int* in_sizes, int n_in,
                              void* d_out, int out_size, void* d_ws, size_t ws_size,
                              hipStream_t stream) {
    const int* X = (const int*)d_in[0];
    const int* Xlen = (const int*)d_in[1];
    const int* sel_b = (const int*)d_in[2];
    const int* sel_t = (const int*)d_in[3];
    const int* eidx = (const int*)d_in[4];
    const float* emb = (const float*)d_in[5];
    const float* w_ih_l0f = (const float*)d_in[6];
    const float* w_hh_l0f = (const float*)d_in[7];
    const float* b_ih_l0f = (const float*)d_in[8];
    const float* b_hh_l0f = (const float*)d_in[9];
    const float* w_ih_l0b = (const float*)d_in[10];
    const float* w_hh_l0b = (const float*)d_in[11];
    const float* b_ih_l0b = (const float*)d_in[12];
    const float* b_hh_l0b = (const float*)d_in[13];
    const float* w_ih_l1f = (const float*)d_in[14];
    const float* w_hh_l1f = (const float*)d_in[15];
    const float* b_ih_l1f = (const float*)d_in[16];
    const float* b_hh_l1f = (const float*)d_in[17];
    const float* w_ih_l1b = (const float*)d_in[18];
    const float* w_hh_l1b = (const float*)d_in[19];
    const float* b_ih_l1b = (const float*)d_in[20];
    const float* b_hh_l1b = (const float*)d_in[21];
    const float* outW = (const float*)d_in[22];
    const float* outb = (const float*)d_in[23];
    const float* expW = (const float*)d_in[24];
    const float* expb = (const float*)d_in[25];

    char* ws = (char*)d_ws;
    float* gates_f = (float*)ws;                                  // 52,428,800 B  [t][n'][b] f32
    float* gates_b = (float*)(ws + 52428800);                     // 52,428,800 B
    _Float16* wp0f = (_Float16*)(ws + 104857600);                 // 2,097,152 B each
    _Float16* wp0b = (_Float16*)(ws + 106954752);
    _Float16* wp1f = (_Float16*)(ws + 109051904);
    _Float16* wp1b = (_Float16*)(ws + 111149056);
    _Float16* hs0  = (_Float16*)(ws + 113246208);                 // 13,107,200 B  [(t*64+b)][1024]
    _Float16* hs1  = (_Float16*)(ws + 126353408);                 // 13,107,200 B
    _Float16* xemb = (_Float16*)(ws + 139460608);                 // 4,096,000 B
    unsigned* flags0 = (unsigned*)(ws + 143556608);               // 4,096 B
    unsigned* flags1 = (unsigned*)(ws + 143560704);               // 4,096 B
    size_t needed = 143564800;
    if (ws_size < needed) return;  // diagnostic: absmax would equal max|ref|
    float* out = (float*)d_out;

    hipMemsetAsync(flags0, 0, 8192, stream);   // zero both layers' flag sets

    embed_kernel<<<(BB * TT * EMBP + 255) / 256, 256, 0, stream>>>(X, emb, xemb);
    wprep_kernel<<<256, 256, 0, stream>>>(w_hh_l0f, w_hh_l0b, w_hh_l1f, w_hh_l1b,
                                          wp0f, wp0b, wp1f, wp1b);

    dim3 gproj(100, 32);
    xproj_mfma_kernel<<<gproj, 256, 0, stream>>>(xemb, w_ih_l0f, b_ih_l0f, b_hh_l0f, gates_f, EMBD, EMBP);
    xproj_mfma_kernel<<<gproj, 256, 0, stream>>>(xemb, w_ih_l0b, b_ih_l0b, b_hh_l0b, gates_b, EMBD, EMBP);

    {
        const float* a0 = gates_f; const float* a1 = gates_b;
        const _Float16* a2 = wp0f; const _Float16* a3 = wp0b;
        const int* a4 = Xlen; _Float16* a5 = hs0; unsigned* a6 = flags0;
        void* args[] = {(void*)&a0, (void*)&a1, (void*)&a2, (void*)&a3,
                        (void*)&a4, (void*)&a5, (void*)&a6};
        hipLaunchCooperativeKernel((const void*)lstm_group_kernel, dim3(64), dim3(512), args, 0, stream);
    }

    xproj_mfma_kernel<<<gproj, 256, 0, stream>>>(hs0, w_ih_l1f, b_ih_l1f, b_hh_l1f, gates_f, 1024, 1024);
    xproj_mfma_kernel<<<gproj, 256, 0, stream>>>(hs0, w_ih_l1b, b_ih_l1b, b_hh_l1b, gates_b, 1024, 1024);

    {
        const float* a0 = gates_f; const float* a1 = gates_b;
        const _Float16* a2 = wp1f; const _Float16* a3 = wp1b;
        const int* a4 = Xlen; _Float16* a5 = hs1; unsigned* a6 = flags1;
        void* args[] = {(void*)&a0, (void*)&a1, (void*)&a2, (void*)&a3,
                        (void*)&a4, (void*)&a5, (void*)&a6};
        hipLaunchCooperativeKernel((const void*)lstm_group_kernel, dim3(64), dim3(512), args, 0, stream);
    }

    ctx_kernel<<<dim3(32, 5), 256, 0, stream>>>(hs1, outW, outb, sel_b, sel_t, out);
    cls_kernel<<<KSEL, 256, 0, stream>>>(hs1, expW, expb, sel_b, sel_t, eidx, out);
}

// Round 6
// 1242.201 us; speedup vs baseline: 9.2479x; 2.5319x over previous
//
#include <hip/hip_runtime.h>
#include <hip/hip_bf16.h>

#define BB 64
#define TT 100
#define KSEL 2048
#define EMBD 300
#define EMBP 320
#define HH 512
#define GG 2048   // 4*H
#define NSYN 16

typedef __attribute__((ext_vector_type(8))) _Float16 f16x8;
typedef __attribute__((ext_vector_type(4))) float f32x4;

__device__ __forceinline__ float sigf(float x) { return 1.f / (1.f + __expf(-x)); }
__device__ __forceinline__ float tanhfast(float x) {
    float e = __expf(-2.f * fabsf(x));
    float r = (1.f - e) / (1.f + e);
    return copysignf(r, x);
}

// ---------------- embedding gather -> fp16, rows in (t*64+b) order ----------------
__global__ void embed_kernel(const int* __restrict__ X, const float* __restrict__ emb,
                             _Float16* __restrict__ xemb) {
    int idx = blockIdx.x * blockDim.x + threadIdx.x;
    int total = BB * TT * EMBP;
    if (idx >= total) return;
    int row = idx / EMBP;
    int col = idx - row * EMBP;
    int b = row & 63, t = row >> 6;
    float v = 0.f;
    if (col < EMBD) v = emb[(size_t)X[b * TT + t] * EMBD + col];
    xemb[idx] = (_Float16)v;
}

// ---------------- W_hh -> fp16 permuted-row copy:  W'[n'][k] = W[pr(n')][k] ----------------
// pr(n') = (n'&3)*512 + (n'>>2)
__global__ void wprep_kernel(const float* __restrict__ w0f, const float* __restrict__ w0b,
                             const float* __restrict__ w1f, const float* __restrict__ w1b,
                             _Float16* __restrict__ o0f, _Float16* __restrict__ o0b,
                             _Float16* __restrict__ o1f, _Float16* __restrict__ o1b) {
    int bid = blockIdx.x;          // 256 blocks
    int mat = bid >> 6;
    int rgrp = (bid & 63) * 32;
    const float* W = mat == 0 ? w0f : mat == 1 ? w0b : mat == 2 ? w1f : w1b;
    _Float16* O = mat == 0 ? o0f : mat == 1 ? o0b : mat == 2 ? o1f : o1b;
    int tid = threadIdx.x;
    int rl = tid >> 3;
    int kc = (tid & 7) * 64;
    int np = rgrp + rl;
    int pr = (np & 3) * 512 + (np >> 2);
    const float* src = W + (size_t)pr * 512 + kc;
    _Float16* dst = O + (size_t)np * 512 + kc;
    for (int i = 0; i < 64; i += 4) {
        float4 v = *(const float4*)(src + i);
        dst[i + 0] = (_Float16)v.x;
        dst[i + 1] = (_Float16)v.y;
        dst[i + 2] = (_Float16)v.z;
        dst[i + 3] = (_Float16)v.w;
    }
}

// ---------------- MFMA fp16 input projection, output transposed gatesT[t][n'][b] ----------------
__global__ void __launch_bounds__(256)
xproj_mfma_kernel(const _Float16* __restrict__ A, const float* __restrict__ W,
                  const float* __restrict__ bih, const float* __restrict__ bhh,
                  float* __restrict__ gatesT, int Kreal, int Kpad) {
    __shared__ _Float16 A_lds[64][40];
    __shared__ _Float16 B_lds[64][40];
    __shared__ float biasl[64];
    int tid = threadIdx.x;
    int t = blockIdx.x;
    int m0 = t * 64, n0 = blockIdx.y * 64;
    if (tid < 64) {
        int n = n0 + tid;
        int pr = (n & 3) * 512 + (n >> 2);
        biasl[tid] = bih[pr] + bhh[pr];
    }
    int w = tid >> 6, l = tid & 63;
    int ml = tid >> 2, kk0 = (tid & 3) * 8;
    f32x4 acc[4] = {};
    __syncthreads();
    for (int k0 = 0; k0 < Kpad; k0 += 32) {
        {
            uint4 v = *(const uint4*)(A + (size_t)(m0 + ml) * Kpad + k0 + kk0);
            *(uint4*)&A_lds[ml][kk0] = v;
        }
        {
            int n = n0 + ml;
            int pr = (n & 3) * 512 + (n >> 2);
            const float* src = W + (size_t)pr * Kreal + k0 + kk0;
            if (k0 + 31 < Kreal) {
                float4 v0 = *(const float4*)(src);
                float4 v1 = *(const float4*)(src + 4);
                B_lds[ml][kk0 + 0] = (_Float16)v0.x; B_lds[ml][kk0 + 1] = (_Float16)v0.y;
                B_lds[ml][kk0 + 2] = (_Float16)v0.z; B_lds[ml][kk0 + 3] = (_Float16)v0.w;
                B_lds[ml][kk0 + 4] = (_Float16)v1.x; B_lds[ml][kk0 + 5] = (_Float16)v1.y;
                B_lds[ml][kk0 + 6] = (_Float16)v1.z; B_lds[ml][kk0 + 7] = (_Float16)v1.w;
            } else {
                for (int i = 0; i < 8; i++) {
                    int k = k0 + kk0 + i;
                    B_lds[ml][kk0 + i] = (k < Kreal) ? (_Float16)src[i] : (_Float16)0.f;
                }
            }
        }
        __syncthreads();
        f16x8 bfrag = *(const f16x8*)&B_lds[w * 16 + (l & 15)][(l >> 4) * 8];
#pragma unroll
        for (int mb = 0; mb < 4; mb++) {
            f16x8 afrag = *(const f16x8*)&A_lds[mb * 16 + (l & 15)][(l >> 4) * 8];
            acc[mb] = __builtin_amdgcn_mfma_f32_16x16x32_f16(afrag, bfrag, acc[mb], 0, 0, 0);
        }
        __syncthreads();
    }
    int n_local = w * 16 + (l & 15);
    float bias = biasl[n_local];
#pragma unroll
    for (int mb = 0; mb < 4; mb++) {
        float4 st;
        st.x = acc[mb][0] + bias;
        st.y = acc[mb][1] + bias;
        st.z = acc[mb][2] + bias;
        st.w = acc[mb][3] + bias;
        *(float4*)&gatesT[((size_t)t * 2048 + n0 + n_local) * 64 + mb * 16 + (l >> 4) * 4] = st;
    }
}

// ---------------- bilstm layer: LDS-resident W + fence-free tagged exchange ----------------
// 128 wgs x 512 thr (cooperative). group g = dir*4+bg? -> g = bid&7: dir = g&1, bg = g>>1.
// member = bid>>3 (16 per group) owns 128 n'-cols; W-slice 128KB in dynamic LDS (swizzled).
// Exchange word u32 = (fp16 h)<<16 | tag, tag = tagbase + step + 1, relaxed SYSTEM atomics,
// 2-slot ring ex[slot][g][16 b][512 j]. No fences anywhere.
__global__ void __launch_bounds__(512, 1)
lstm_tag_kernel(const float* __restrict__ gTf, const float* __restrict__ gTb,
                const _Float16* __restrict__ wpf, const _Float16* __restrict__ wpb,
                const int* __restrict__ lengths, _Float16* __restrict__ hs,
                unsigned* __restrict__ ex, int tagbase) {
    extern __shared__ char smem[];
    uint4* wlds = (uint4*)smem;                       // 131072 B: [128 c][64 gi] swizzled
    uint4* hlds = (uint4*)(smem + 131072);            // 16384 B:  [16 b][64 gi] swizzled
    _Float16* hpack = (_Float16*)(smem + 147456);     // 1024 B:   [16 b][32 jl]
    int bid = blockIdx.x;
    int g = bid & 7, mem = bid >> 3;
    int dir = g & 1, bg = g >> 1;
    const float* gT = dir ? gTb : gTf;
    const _Float16* wp = dir ? wpb : wpf;
    int tid = threadIdx.x;
    int w = tid >> 6, l = tid & 63;
    int lc = l & 15, hi = l >> 4;
    int q = lc & 3;
    int nb = mem * 128;
    int c = w * 16 + lc;                 // member-local col 0..127

    // ---- stage W-slice into LDS (once), XOR-swizzled granules ----
    {
        const _Float16* wsrc = wp + (size_t)nb * 512;
        for (int i = 0; i < 16; i++) {
            int idx = i * 512 + tid;
            int cc = idx >> 6, gi = idx & 63;
            uint4 v = *(const uint4*)(wsrc + (size_t)cc * 512 + gi * 8);
            wlds[(cc << 6) | (gi ^ (cc & 7))] = v;
        }
    }
    float cst[4] = {};
    float hst[4] = {};
    int lenv[4];
#pragma unroll
    for (int r = 0; r < 4; r++) lenv[r] = lengths[bg * 16 + hi * 4 + r];
    __syncthreads();

    for (int s = 0; s < TT; s++) {
        int t = dir ? (TT - 1 - s) : s;
        // gate init (issued before poll)
        f32x4 acc;
        {
            float4 gv = *(const float4*)(gT + ((size_t)t * 2048 + nb + c) * 64 + bg * 16 + hi * 4);
            acc[0] = gv.x; acc[1] = gv.y; acc[2] = gv.z; acc[3] = gv.w;
        }
        if (s > 0) {
            // ---- fence-free tagged poll: (b=i, j=tid) for i in 0..15 ----
            const unsigned* exrow = ex + ((size_t)(((s - 1) & 1) * 8 + g) * 16) * 512;
            unsigned want = (unsigned)(tagbase + s);
            unsigned vals[16];
            while (true) {
                bool ok = true;
#pragma unroll
                for (int i = 0; i < 16; i++)
                    vals[i] = __hip_atomic_load(exrow + i * 512 + tid, __ATOMIC_RELAXED,
                                                __HIP_MEMORY_SCOPE_SYSTEM);
#pragma unroll
                for (int i = 0; i < 16; i++) ok &= ((vals[i] & 0xFFFFu) == want);
                if (ok) break;
            }
            // ---- stage payloads into swizzled hlds ----
            _Float16* hf = (_Float16*)hlds;
            int gi = tid >> 3, el = tid & 7;
#pragma unroll
            for (int i = 0; i < 16; i++) {
                unsigned short hb = (unsigned short)(vals[i] >> 16);
                hf[(((i << 6) | (gi ^ (i & 7))) << 3) + el] = __builtin_bit_cast(_Float16, hb);
            }
            __syncthreads();
            // ---- MFMA: 16 k-slices ----
#pragma unroll
            for (int ks = 0; ks < 16; ks++) {
                int gg = (ks * 4 + hi);
                f16x8 af = *(const f16x8*)((const char*)hlds + (((lc << 6) | (gg ^ (lc & 7))) << 4));
                f16x8 bf = *(const f16x8*)((const char*)wlds + (((c << 6) | (gg ^ (lc & 7))) << 4));
                acc = __builtin_amdgcn_mfma_f32_16x16x32_f16(af, bf, acc, 0, 0, 0);
            }
        }
        // ---- epilogue: 4-lane gate transpose + state update ----
#pragma unroll
        for (int r = 0; r < 4; r++) {
            float pre = acc[r];
            float sg = sigf(pre), th = tanhfast(pre);
            float a = (q == 2) ? th : sg;
            float p1 = __shfl_xor(a, 1);
            float p2 = __shfl_xor(a, 2);
            float p3 = __shfl_xor(p1, 2);
            float gi_ = q == 0 ? a : q == 1 ? p1 : q == 2 ? p2 : p3;
            float gf_ = q == 0 ? p1 : q == 1 ? a : q == 2 ? p3 : p2;
            float gg_ = q == 0 ? p2 : q == 1 ? p3 : q == 2 ? a : p1;
            float go_ = q == 0 ? p3 : q == 1 ? p2 : q == 2 ? p1 : a;
            float cn = gf_ * cst[r] + gi_ * gg_;
            float hn = go_ * tanhfast(cn);
            if (t < lenv[r]) { cst[r] = cn; hst[r] = hn; }
            if (q == 0) hpack[(hi * 4 + r) * 32 + w * 4 + (lc >> 2)] = (_Float16)hst[r];
        }
        __syncthreads();
        // ---- publish: 1 tagged u32 + 1 plain fp16 per thread ----
        {
            int bb = tid >> 5, jl = tid & 31;
            _Float16 hv = hpack[bb * 32 + jl];
            unsigned wv = ((unsigned)__builtin_bit_cast(unsigned short, hv) << 16)
                        | (unsigned)(tagbase + s + 1);
            __hip_atomic_store(ex + (((size_t)(s & 1) * 8 + g) * 16 + bb) * 512 + mem * 32 + jl,
                               wv, __ATOMIC_RELAXED, __HIP_MEMORY_SCOPE_SYSTEM);
            hs[((size_t)(t * 64 + bg * 16 + bb)) * 1024 + dir * 512 + mem * 32 + jl] = hv;
        }
        __syncthreads();
    }
}

// ---------------- ctx = xsel @ out_W^T + out_b ----------------
__global__ void ctx_kernel(const _Float16* __restrict__ hs1, const float* __restrict__ outW,
                           const float* __restrict__ outb, const int* __restrict__ sel_b,
                           const int* __restrict__ sel_t, float* __restrict__ out) {
    __shared__ float As[16][68];
    __shared__ float Bs[16][68];
    __shared__ int rowbase[64];
    int tid = threadIdx.x;
    int m0 = blockIdx.x * 64, n0 = blockIdx.y * 64;
    if (tid < 64) {
        int m = m0 + tid;
        rowbase[tid] = (sel_t[m] * 64 + sel_b[m]) * 1024;
    }
    __syncthreads();
    int tx = tid & 15, ty = tid >> 4;
    float acc[4][4] = {};
    for (int k0 = 0; k0 < 1024; k0 += 16) {
        for (int e = tid; e < 1024; e += 256) {
            int ml = e >> 4, k = e & 15;
            As[k][ml] = (float)hs1[(size_t)rowbase[ml] + k0 + k];
        }
        for (int e = tid; e < 1024; e += 256) {
            int nl = e >> 4, k = e & 15;
            int n = n0 + nl;
            Bs[k][nl] = (n < EMBD) ? outW[(size_t)n * 1024 + k0 + k] : 0.f;
        }
        __syncthreads();
#pragma unroll
        for (int kk = 0; kk < 16; kk++) {
            float4 a4 = *(const float4*)&As[kk][ty * 4];
            float4 b4 = *(const float4*)&Bs[kk][tx * 4];
            float av[4] = {a4.x, a4.y, a4.z, a4.w};
            float bv[4] = {b4.x, b4.y, b4.z, b4.w};
#pragma unroll
            for (int i = 0; i < 4; i++)
#pragma unroll
                for (int jj = 0; jj < 4; jj++) acc[i][jj] += av[i] * bv[jj];
        }
        __syncthreads();
    }
    for (int i = 0; i < 4; i++) {
        int m = m0 + ty * 4 + i;
        for (int jj = 0; jj < 4; jj++) {
            int n = n0 + tx * 4 + jj;
            if (n < EMBD) out[(size_t)m * EMBD + n] = acc[i][jj] + outb[n];
        }
    }
}

// ---------------- cls = einsum('ksd,kd->ks', exp_W[eidx], xsel) + exp_b[eidx] ----------------
__global__ void cls_kernel(const _Float16* __restrict__ hs1, const float* __restrict__ expW,
                           const float* __restrict__ expb, const int* __restrict__ sel_b,
                           const int* __restrict__ sel_t, const int* __restrict__ eidx,
                           float* __restrict__ out) {
    __shared__ float xr[1024];
    int r = blockIdx.x;
    int tid = threadIdx.x;
    int e = eidx[r];
    int base = (sel_t[r] * 64 + sel_b[r]) * 1024;
    for (int qq = tid; qq < 1024; qq += 256) xr[qq] = (float)hs1[(size_t)base + qq];
    __syncthreads();
    int lane = tid & 63, wid = tid >> 6;
    for (int p = 0; p < 4; p++) {
        int s = p * 4 + wid;
        const float* wrow = expW + ((size_t)e * NSYN + s) * 1024;
        float partial = 0.f;
#pragma unroll
        for (int i = 0; i < 16; i++) {
            int k = lane + 64 * i;
            partial += xr[k] * wrow[k];
        }
        for (int off = 32; off; off >>= 1) partial += __shfl_down(partial, off);
        if (lane == 0) out[(size_t)KSEL * EMBD + (size_t)r * NSYN + s] = partial + expb[e * NSYN + s];
    }
}

extern "C" void kernel_launch(void* const* d_in, const int* in_sizes, int n_in,
                              void* d_out, int out_size, void* d_ws, size_t ws_size,
                              hipStream_t stream) {
    const int* X = (const int*)d_in[0];
    const int* Xlen = (const int*)d_in[1];
    const int* sel_b = (const int*)d_in[2];
    const int* sel_t = (const int*)d_in[3];
    const int* eidx = (const int*)d_in[4];
    const float* emb = (const float*)d_in[5];
    const float* w_ih_l0f = (const float*)d_in[6];
    const float* w_hh_l0f = (const float*)d_in[7];
    const float* b_ih_l0f = (const float*)d_in[8];
    const float* b_hh_l0f = (const float*)d_in[9];
    const float* w_ih_l0b = (const float*)d_in[10];
    const float* w_hh_l0b = (const float*)d_in[11];
    const float* b_ih_l0b = (const float*)d_in[12];
    const float* b_hh_l0b = (const float*)d_in[13];
    const float* w_ih_l1f = (const float*)d_in[14];
    const float* w_hh_l1f = (const float*)d_in[15];
    const float* b_ih_l1f = (const float*)d_in[16];
    const float* b_hh_l1f = (const float*)d_in[17];
    const float* w_ih_l1b = (const float*)d_in[18];
    const float* w_hh_l1b = (const float*)d_in[19];
    const float* b_ih_l1b = (const float*)d_in[20];
    const float* b_hh_l1b = (const float*)d_in[21];
    const float* outW = (const float*)d_in[22];
    const float* outb = (const float*)d_in[23];
    const float* expW = (const float*)d_in[24];
    const float* expb = (const float*)d_in[25];

    char* ws = (char*)d_ws;
    float* gates_f = (float*)ws;                                  // 52,428,800 B  [t][n'][b] f32
    float* gates_b = (float*)(ws + 52428800);                     // 52,428,800 B
    _Float16* wp0f = (_Float16*)(ws + 104857600);                 // 2,097,152 B each
    _Float16* wp0b = (_Float16*)(ws + 106954752);
    _Float16* wp1f = (_Float16*)(ws + 109051904);
    _Float16* wp1b = (_Float16*)(ws + 111149056);
    _Float16* hs0  = (_Float16*)(ws + 113246208);                 // 13,107,200 B  [(t*64+b)][1024]
    _Float16* hs1  = (_Float16*)(ws + 126353408);                 // 13,107,200 B
    _Float16* xemb = (_Float16*)(ws + 139460608);                 // 4,096,000 B
    unsigned* exbuf = (unsigned*)(ws + 143556608);                // 524,288 B (2-slot tagged ring)
    size_t needed = 144080896;
    if (ws_size < needed) return;  // diagnostic: absmax would equal max|ref|
    float* out = (float*)d_out;

    hipFuncSetAttribute((const void*)lstm_tag_kernel,
                        hipFuncAttributeMaxDynamicSharedMemorySize, 148480);

    hipMemsetAsync(exbuf, 0, 524288, stream);   // clear tags (replay-safe)

    embed_kernel<<<(BB * TT * EMBP + 255) / 256, 256, 0, stream>>>(X, emb, xemb);
    wprep_kernel<<<256, 256, 0, stream>>>(w_hh_l0f, w_hh_l0b, w_hh_l1f, w_hh_l1b,
                                          wp0f, wp0b, wp1f, wp1b);

    dim3 gproj(100, 32);
    xproj_mfma_kernel<<<gproj, 256, 0, stream>>>(xemb, w_ih_l0f, b_ih_l0f, b_hh_l0f, gates_f, EMBD, EMBP);
    xproj_mfma_kernel<<<gproj, 256, 0, stream>>>(xemb, w_ih_l0b, b_ih_l0b, b_hh_l0b, gates_b, EMBD, EMBP);

    {
        const float* a0 = gates_f; const float* a1 = gates_b;
        const _Float16* a2 = wp0f; const _Float16* a3 = wp0b;
        const int* a4 = Xlen; _Float16* a5 = hs0; unsigned* a6 = exbuf; int a7 = 0;
        void* args[] = {(void*)&a0, (void*)&a1, (void*)&a2, (void*)&a3,
                        (void*)&a4, (void*)&a5, (void*)&a6, (void*)&a7};
        hipLaunchCooperativeKernel((const void*)lstm_tag_kernel, dim3(128), dim3(512), args, 148480, stream);
    }

    xproj_mfma_kernel<<<gproj, 256, 0, stream>>>(hs0, w_ih_l1f, b_ih_l1f, b_hh_l1f, gates_f, 1024, 1024);
    xproj_mfma_kernel<<<gproj, 256, 0, stream>>>(hs0, w_ih_l1b, b_ih_l1b, b_hh_l1b, gates_b, 1024, 1024);

    {
        const float* a0 = gates_f; const float* a1 = gates_b;
        const _Float16* a2 = wp1f; const _Float16* a3 = wp1b;
        const int* a4 = Xlen; _Float16* a5 = hs1; unsigned* a6 = exbuf; int a7 = 128;
        void* args[] = {(void*)&a0, (void*)&a1, (void*)&a2, (void*)&a3,
                        (void*)&a4, (void*)&a5, (void*)&a6, (void*)&a7};
        hipLaunchCooperativeKernel((const void*)lstm_tag_kernel, dim3(128), dim3(512), args, 148480, stream);
    }

    ctx_kernel<<<dim3(32, 5), 256, 0, stream>>>(hs1, outW, outb, sel_b, sel_t, out);
    cls_kernel<<<KSEL, 256, 0, stream>>>(hs1, expW, expb, sel_b, sel_t, eidx, out);
}

// Round 8
// 1185.874 us; speedup vs baseline: 9.6872x; 1.0475x over previous
//
#include <hip/hip_runtime.h>
#include <hip/hip_bf16.h>

#define BB 64
#define TT 100
#define KSEL 2048
#define EMBD 300
#define EMBP 320
#define HH 512
#define GG 2048   // 4*H
#define NSYN 16

typedef __attribute__((ext_vector_type(8))) _Float16 f16x8;
typedef __attribute__((ext_vector_type(4))) float f32x4;

__device__ __forceinline__ float sigf(float x) { return 1.f / (1.f + __expf(-x)); }
__device__ __forceinline__ float tanhfast(float x) {
    float e = __expf(-2.f * fabsf(x));
    float r = (1.f - e) / (1.f + e);
    return copysignf(r, x);
}

// ---------------- embedding gather -> fp16, rows in (t*64+b) order ----------------
__global__ void embed_kernel(const int* __restrict__ X, const float* __restrict__ emb,
                             _Float16* __restrict__ xemb) {
    int idx = blockIdx.x * blockDim.x + threadIdx.x;
    int total = BB * TT * EMBP;
    if (idx >= total) return;
    int row = idx / EMBP;
    int col = idx - row * EMBP;
    int b = row & 63, t = row >> 6;
    float v = 0.f;
    if (col < EMBD) v = emb[(size_t)X[b * TT + t] * EMBD + col];
    xemb[idx] = (_Float16)v;
}

// ---------------- W_hh -> fp16 permuted-row copy:  W'[n'][k] = W[pr(n')][k] ----------------
// pr(n') = (n'&3)*512 + (n'>>2)
__global__ void wprep_kernel(const float* __restrict__ w0f, const float* __restrict__ w0b,
                             const float* __restrict__ w1f, const float* __restrict__ w1b,
                             _Float16* __restrict__ o0f, _Float16* __restrict__ o0b,
                             _Float16* __restrict__ o1f, _Float16* __restrict__ o1b) {
    int bid = blockIdx.x;          // 256 blocks
    int mat = bid >> 6;
    int rgrp = (bid & 63) * 32;
    const float* W = mat == 0 ? w0f : mat == 1 ? w0b : mat == 2 ? w1f : w1b;
    _Float16* O = mat == 0 ? o0f : mat == 1 ? o0b : mat == 2 ? o1f : o1b;
    int tid = threadIdx.x;
    int rl = tid >> 3;
    int kc = (tid & 7) * 64;
    int np = rgrp + rl;
    int pr = (np & 3) * 512 + (np >> 2);
    const float* src = W + (size_t)pr * 512 + kc;
    _Float16* dst = O + (size_t)np * 512 + kc;
    for (int i = 0; i < 64; i += 4) {
        float4 v = *(const float4*)(src + i);
        dst[i + 0] = (_Float16)v.x;
        dst[i + 1] = (_Float16)v.y;
        dst[i + 2] = (_Float16)v.z;
        dst[i + 3] = (_Float16)v.w;
    }
}

// ---------------- W_ih -> fp16 permuted [n'][Kpad] (zero-padded) ----------------
__global__ void wih_prep_kernel(const float* __restrict__ Wf, const float* __restrict__ Wb,
                                _Float16* __restrict__ Of, _Float16* __restrict__ Ob,
                                int Kreal, int Kpad) {
    int dir = blockIdx.y;
    const float* W = dir ? Wb : Wf;
    _Float16* O = dir ? Ob : Of;
    int total = 2048 * Kpad;
    for (int idx = blockIdx.x * 256 + threadIdx.x; idx < total; idx += gridDim.x * 256) {
        int np = idx / Kpad, k = idx - np * Kpad;
        int pr = (np & 3) * 512 + (np >> 2);
        O[idx] = (k < Kreal) ? (_Float16)W[(size_t)pr * Kreal + k] : (_Float16)0.f;
    }
}

// ---------------- MFMA fp16 input projection, 64x128 tile, f/b merged ----------------
// A fp16 [6400][Kpad] rows m = t*64+b; B = prepped fp16 W'[2048][Kpad].
// Output gatesT[t][n'][b] f32. blockIdx: x = t, y = n-tile(128), z = dir.
__global__ void __launch_bounds__(256)
xproj2_kernel(const _Float16* __restrict__ A,
              const _Float16* __restrict__ Wpf, const _Float16* __restrict__ Wpb,
              const float* __restrict__ bihf, const float* __restrict__ bhhf,
              const float* __restrict__ bihb, const float* __restrict__ bhhb,
              float* __restrict__ gTf, float* __restrict__ gTb, int Kpad) {
    __shared__ _Float16 A_lds[64][40];
    __shared__ _Float16 B_lds[128][40];
    __shared__ float biasl[128];
    int tid = threadIdx.x;
    int t = blockIdx.x;
    int n0 = blockIdx.y * 128;
    int dir = blockIdx.z;
    const _Float16* W = dir ? Wpb : Wpf;
    const float* bih = dir ? bihb : bihf;
    const float* bhh = dir ? bhhb : bhhf;
    float* gT = dir ? gTb : gTf;
    if (tid < 128) {
        int n = n0 + tid;
        int pr = (n & 3) * 512 + (n >> 2);
        biasl[tid] = bih[pr] + bhh[pr];
    }
    int w = tid >> 6, l = tid & 63;
    int ml = tid >> 2, kk0 = (tid & 3) * 8;
    f32x4 acc[2][4] = {};
    __syncthreads();
    for (int k0 = 0; k0 < Kpad; k0 += 32) {
        *(uint4*)&A_lds[ml][kk0] = *(const uint4*)(A + (size_t)(t * 64 + ml) * Kpad + k0 + kk0);
#pragma unroll
        for (int h = 0; h < 2; h++) {
            int idx = h * 256 + tid;
            int nl = idx >> 2, kb = (idx & 3) * 8;
            *(uint4*)&B_lds[nl][kb] = *(const uint4*)(W + (size_t)(n0 + nl) * Kpad + k0 + kb);
        }
        __syncthreads();
#pragma unroll
        for (int nt = 0; nt < 2; nt++) {
            f16x8 bfrag = *(const f16x8*)&B_lds[nt * 64 + w * 16 + (l & 15)][(l >> 4) * 8];
#pragma unroll
            for (int mb = 0; mb < 4; mb++) {
                f16x8 afrag = *(const f16x8*)&A_lds[mb * 16 + (l & 15)][(l >> 4) * 8];
                acc[nt][mb] = __builtin_amdgcn_mfma_f32_16x16x32_f16(afrag, bfrag, acc[nt][mb], 0, 0, 0);
            }
        }
        __syncthreads();
    }
#pragma unroll
    for (int nt = 0; nt < 2; nt++) {
        int n_local = nt * 64 + w * 16 + (l & 15);
        float bias = biasl[n_local];
#pragma unroll
        for (int mb = 0; mb < 4; mb++) {
            float4 st;
            st.x = acc[nt][mb][0] + bias;
            st.y = acc[nt][mb][1] + bias;
            st.z = acc[nt][mb][2] + bias;
            st.w = acc[nt][mb][3] + bias;
            *(float4*)&gT[((size_t)t * 2048 + n0 + n_local) * 64 + mb * 16 + (l >> 4) * 4] = st;
        }
    }
}

// ---------------- bilstm layer: R6-proven protocol (LDS W + fence-free tagged exchange) ----
// 128 wgs x 512 thr (cooperative). g = bid&7: dir = g&1, bg = g>>1. member = bid>>3 owns
// 128 n'-cols (W-slice 128KB in LDS). Exchange word u32 = (fp16 h)<<16 | tag, relaxed
// SYSTEM atomics, 2-slot ring ex[slot][g][16 b][512 j]. No fences anywhere.
// Only change vs R6: MFMA split into two independent 8-deep chains (register-only).
__global__ void __launch_bounds__(512, 1)
lstm_tag_kernel(const float* __restrict__ gTf, const float* __restrict__ gTb,
                const _Float16* __restrict__ wpf, const _Float16* __restrict__ wpb,
                const int* __restrict__ lengths, _Float16* __restrict__ hs,
                unsigned* __restrict__ ex, int tagbase) {
    extern __shared__ char smem[];
    uint4* wlds = (uint4*)smem;                       // 131072 B: [128 c][64 gi] swizzled
    uint4* hlds = (uint4*)(smem + 131072);            // 16384 B:  [16 b][64 gi] swizzled
    _Float16* hpack = (_Float16*)(smem + 147456);     // 1024 B:   [16 b][32 jl]
    int bid = blockIdx.x;
    int g = bid & 7, mem = bid >> 3;
    int dir = g & 1, bg = g >> 1;
    const float* gT = dir ? gTb : gTf;
    const _Float16* wp = dir ? wpb : wpf;
    int tid = threadIdx.x;
    int w = tid >> 6, l = tid & 63;
    int lc = l & 15, hi = l >> 4;
    int q = lc & 3;
    int nb = mem * 128;
    int c = w * 16 + lc;                 // member-local col 0..127

    // ---- stage W-slice into LDS (once), XOR-swizzled granules ----
    {
        const _Float16* wsrc = wp + (size_t)nb * 512;
        for (int i = 0; i < 16; i++) {
            int idx = i * 512 + tid;
            int cc = idx >> 6, gi = idx & 63;
            uint4 v = *(const uint4*)(wsrc + (size_t)cc * 512 + gi * 8);
            wlds[(cc << 6) | (gi ^ (cc & 7))] = v;
        }
    }
    float cst[4] = {};
    float hst[4] = {};
    int lenv[4];
#pragma unroll
    for (int r = 0; r < 4; r++) lenv[r] = lengths[bg * 16 + hi * 4 + r];
    __syncthreads();

    for (int s = 0; s < TT; s++) {
        int t = dir ? (TT - 1 - s) : s;
        // gate init (issued before poll)
        f32x4 acc, acc2;
        {
            float4 gv = *(const float4*)(gT + ((size_t)t * 2048 + nb + c) * 64 + bg * 16 + hi * 4);
            acc[0] = gv.x; acc[1] = gv.y; acc[2] = gv.z; acc[3] = gv.w;
            acc2[0] = 0.f; acc2[1] = 0.f; acc2[2] = 0.f; acc2[3] = 0.f;
        }
        if (s > 0) {
            // ---- fence-free tagged poll: (b=i, j=tid) for i in 0..15 ----
            const unsigned* exrow = ex + ((size_t)(((s - 1) & 1) * 8 + g) * 16) * 512;
            unsigned want = (unsigned)(tagbase + s);
            unsigned vals[16];
            while (true) {
                bool ok = true;
#pragma unroll
                for (int i = 0; i < 16; i++)
                    vals[i] = __hip_atomic_load(exrow + i * 512 + tid, __ATOMIC_RELAXED,
                                                __HIP_MEMORY_SCOPE_SYSTEM);
#pragma unroll
                for (int i = 0; i < 16; i++) ok &= ((vals[i] & 0xFFFFu) == want);
                if (ok) break;
            }
            // ---- stage payloads into swizzled hlds ----
            {
                _Float16* hf = (_Float16*)hlds;
                int gi = tid >> 3, el = tid & 7;
#pragma unroll
                for (int i = 0; i < 16; i++) {
                    unsigned short hb = (unsigned short)(vals[i] >> 16);
                    hf[(((i << 6) | (gi ^ (i & 7))) << 3) + el] = __builtin_bit_cast(_Float16, hb);
                }
            }
            __syncthreads();
            // ---- MFMA: 16 k-slices, two independent 8-deep chains ----
#pragma unroll
            for (int ks = 0; ks < 16; ks += 2) {
                int gg0 = ks * 4 + hi;
                int gg1 = (ks + 1) * 4 + hi;
                f16x8 af0 = *(const f16x8*)((const char*)hlds + (((lc << 6) | (gg0 ^ (lc & 7))) << 4));
                f16x8 bf0 = *(const f16x8*)((const char*)wlds + (((c << 6) | (gg0 ^ (lc & 7))) << 4));
                f16x8 af1 = *(const f16x8*)((const char*)hlds + (((lc << 6) | (gg1 ^ (lc & 7))) << 4));
                f16x8 bf1 = *(const f16x8*)((const char*)wlds + (((c << 6) | (gg1 ^ (lc & 7))) << 4));
                acc  = __builtin_amdgcn_mfma_f32_16x16x32_f16(af0, bf0, acc, 0, 0, 0);
                acc2 = __builtin_amdgcn_mfma_f32_16x16x32_f16(af1, bf1, acc2, 0, 0, 0);
            }
            acc[0] += acc2[0]; acc[1] += acc2[1]; acc[2] += acc2[2]; acc[3] += acc2[3];
            __syncthreads();   // MFMA readers done before next step's hlds overwrite
        }
        // ---- epilogue: 4-lane gate transpose + state update ----
#pragma unroll
        for (int r = 0; r < 4; r++) {
            float pre = acc[r];
            float sg = sigf(pre), th = tanhfast(pre);
            float a = (q == 2) ? th : sg;
            float p1 = __shfl_xor(a, 1);
            float p2 = __shfl_xor(a, 2);
            float p3 = __shfl_xor(p1, 2);
            float gi_ = q == 0 ? a : q == 1 ? p1 : q == 2 ? p2 : p3;
            float gf_ = q == 0 ? p1 : q == 1 ? a : q == 2 ? p3 : p2;
            float gg_ = q == 0 ? p2 : q == 1 ? p3 : q == 2 ? a : p1;
            float go_ = q == 0 ? p3 : q == 1 ? p2 : q == 2 ? p1 : a;
            float cn = gf_ * cst[r] + gi_ * gg_;
            float hn = go_ * tanhfast(cn);
            if (t < lenv[r]) { cst[r] = cn; hst[r] = hn; }
            if (q == 0) hpack[(hi * 4 + r) * 32 + w * 4 + (lc >> 2)] = (_Float16)hst[r];
        }
        __syncthreads();
        // ---- publish: 1 tagged u32 + 1 plain fp16 per thread ----
        {
            int bb = tid >> 5, jl = tid & 31;
            _Float16 hv = hpack[bb * 32 + jl];
            unsigned wv = ((unsigned)__builtin_bit_cast(unsigned short, hv) << 16)
                        | (unsigned)(tagbase + s + 1);
            __hip_atomic_store(ex + (((size_t)(s & 1) * 8 + g) * 16 + bb) * 512 + mem * 32 + jl,
                               wv, __ATOMIC_RELAXED, __HIP_MEMORY_SCOPE_SYSTEM);
            hs[((size_t)(t * 64 + bg * 16 + bb)) * 1024 + dir * 512 + mem * 32 + jl] = hv;
        }
        __syncthreads();
    }
}

// ---------------- ctx = xsel @ out_W^T + out_b ----------------
__global__ void ctx_kernel(const _Float16* __restrict__ hs1, const float* __restrict__ outW,
                           const float* __restrict__ outb, const int* __restrict__ sel_b,
                           const int* __restrict__ sel_t, float* __restrict__ out) {
    __shared__ float As[16][68];
    __shared__ float Bs[16][68];
    __shared__ int rowbase[64];
    int tid = threadIdx.x;
    int m0 = blockIdx.x * 64, n0 = blockIdx.y * 64;
    if (tid < 64) {
        int m = m0 + tid;
        rowbase[tid] = (sel_t[m] * 64 + sel_b[m]) * 1024;
    }
    __syncthreads();
    int tx = tid & 15, ty = tid >> 4;
    float acc[4][4] = {};
    for (int k0 = 0; k0 < 1024; k0 += 16) {
        for (int e = tid; e < 1024; e += 256) {
            int ml = e >> 4, k = e & 15;
            As[k][ml] = (float)hs1[(size_t)rowbase[ml] + k0 + k];
        }
        for (int e = tid; e < 1024; e += 256) {
            int nl = e >> 4, k = e & 15;
            int n = n0 + nl;
            Bs[k][nl] = (n < EMBD) ? outW[(size_t)n * 1024 + k0 + k] : 0.f;
        }
        __syncthreads();
#pragma unroll
        for (int kk = 0; kk < 16; kk++) {
            float4 a4 = *(const float4*)&As[kk][ty * 4];
            float4 b4 = *(const float4*)&Bs[kk][tx * 4];
            float av[4] = {a4.x, a4.y, a4.z, a4.w};
            float bv[4] = {b4.x, b4.y, b4.z, b4.w};
#pragma unroll
            for (int i = 0; i < 4; i++)
#pragma unroll
                for (int jj = 0; jj < 4; jj++) acc[i][jj] += av[i] * bv[jj];
        }
        __syncthreads();
    }
    for (int i = 0; i < 4; i++) {
        int m = m0 + ty * 4 + i;
        for (int jj = 0; jj < 4; jj++) {
            int n = n0 + tx * 4 + jj;
            if (n < EMBD) out[(size_t)m * EMBD + n] = acc[i][jj] + outb[n];
        }
    }
}

// ---------------- cls = einsum('ksd,kd->ks', exp_W[eidx], xsel) + exp_b[eidx] ----------------
__global__ void cls_kernel(const _Float16* __restrict__ hs1, const float* __restrict__ expW,
                           const float* __restrict__ expb, const int* __restrict__ sel_b,
                           const int* __restrict__ sel_t, const int* __restrict__ eidx,
                           float* __restrict__ out) {
    __shared__ float xr[1024];
    int r = blockIdx.x;
    int tid = threadIdx.x;
    int e = eidx[r];
    int base = (sel_t[r] * 64 + sel_b[r]) * 1024;
    for (int qq = tid; qq < 1024; qq += 256) xr[qq] = (float)hs1[(size_t)base + qq];
    __syncthreads();
    int lane = tid & 63, wid = tid >> 6;
    for (int p = 0; p < 4; p++) {
        int s = p * 4 + wid;
        const float* wrow = expW + ((size_t)e * NSYN + s) * 1024;
        float partial = 0.f;
#pragma unroll
        for (int i = 0; i < 16; i++) {
            int k = lane + 64 * i;
            partial += xr[k] * wrow[k];
        }
        for (int off = 32; off; off >>= 1) partial += __shfl_down(partial, off);
        if (lane == 0) out[(size_t)KSEL * EMBD + (size_t)r * NSYN + s] = partial + expb[e * NSYN + s];
    }
}

extern "C" void kernel_launch(void* const* d_in, const int* in_sizes, int n_in,
                              void* d_out, int out_size, void* d_ws, size_t ws_size,
                              hipStream_t stream) {
    const int* X = (const int*)d_in[0];
    const int* Xlen = (const int*)d_in[1];
    const int* sel_b = (const int*)d_in[2];
    const int* sel_t = (const int*)d_in[3];
    const int* eidx = (const int*)d_in[4];
    const float* emb = (const float*)d_in[5];
    const float* w_ih_l0f = (const float*)d_in[6];
    const float* w_hh_l0f = (const float*)d_in[7];
    const float* b_ih_l0f = (const float*)d_in[8];
    const float* b_hh_l0f = (const float*)d_in[9];
    const float* w_ih_l0b = (const float*)d_in[10];
    const float* w_hh_l0b = (const float*)d_in[11];
    const float* b_ih_l0b = (const float*)d_in[12];
    const float* b_hh_l0b = (const float*)d_in[13];
    const float* w_ih_l1f = (const float*)d_in[14];
    const float* w_hh_l1f = (const float*)d_in[15];
    const float* b_ih_l1f = (const float*)d_in[16];
    const float* b_hh_l1f = (const float*)d_in[17];
    const float* w_ih_l1b = (const float*)d_in[18];
    const float* w_hh_l1b = (const float*)d_in[19];
    const float* b_ih_l1b = (const float*)d_in[20];
    const float* b_hh_l1b = (const float*)d_in[21];
    const float* outW = (const float*)d_in[22];
    const float* outb = (const float*)d_in[23];
    const float* expW = (const float*)d_in[24];
    const float* expb = (const float*)d_in[25];

    char* ws = (char*)d_ws;
    float* gates_f = (float*)ws;                                  // 52,428,800 B  [t][n'][b] f32
    float* gates_b = (float*)(ws + 52428800);                     // 52,428,800 B
    _Float16* wp0f = (_Float16*)(ws + 104857600);                 // 2,097,152 B each
    _Float16* wp0b = (_Float16*)(ws + 106954752);
    _Float16* wp1f = (_Float16*)(ws + 109051904);
    _Float16* wp1b = (_Float16*)(ws + 111149056);
    _Float16* hs0  = (_Float16*)(ws + 113246208);                 // 13,107,200 B  [(t*64+b)][1024]
    _Float16* hs1  = (_Float16*)(ws + 126353408);                 // 13,107,200 B
    _Float16* xemb = (_Float16*)(ws + 139460608);                 // 4,096,000 B
    unsigned* exbuf = (unsigned*)(ws + 143556608);                // 524,288 B (2-slot tagged ring)
    _Float16* wi0f = (_Float16*)(ws + 144080896);                 // 1,310,720 B  [2048][320]
    _Float16* wi0b = (_Float16*)(ws + 145391616);                 // 1,310,720 B
    _Float16* wi1f = (_Float16*)(ws + 146702336);                 // 4,194,304 B  [2048][1024]
    _Float16* wi1b = (_Float16*)(ws + 150896640);                 // 4,194,304 B
    size_t needed = 155090944;
    if (ws_size < needed) return;  // diagnostic: absmax would equal max|ref|
    float* out = (float*)d_out;

    hipFuncSetAttribute((const void*)lstm_tag_kernel,
                        hipFuncAttributeMaxDynamicSharedMemorySize, 148480);

    hipMemsetAsync(exbuf, 0, 524288, stream);   // clear tags (replay-safe)

    embed_kernel<<<(BB * TT * EMBP + 255) / 256, 256, 0, stream>>>(X, emb, xemb);
    wprep_kernel<<<256, 256, 0, stream>>>(w_hh_l0f, w_hh_l0b, w_hh_l1f, w_hh_l1b,
                                          wp0f, wp0b, wp1f, wp1b);
    wih_prep_kernel<<<dim3(512, 2), 256, 0, stream>>>(w_ih_l0f, w_ih_l0b, wi0f, wi0b, EMBD, EMBP);
    wih_prep_kernel<<<dim3(512, 2), 256, 0, stream>>>(w_ih_l1f, w_ih_l1b, wi1f, wi1b, 1024, 1024);

    xproj2_kernel<<<dim3(100, 16, 2), 256, 0, stream>>>(xemb, wi0f, wi0b,
        b_ih_l0f, b_hh_l0f, b_ih_l0b, b_hh_l0b, gates_f, gates_b, EMBP);

    {
        const float* a0 = gates_f; const float* a1 = gates_b;
        const _Float16* a2 = wp0f; const _Float16* a3 = wp0b;
        const int* a4 = Xlen; _Float16* a5 = hs0; unsigned* a6 = exbuf; int a7 = 0;
        void* args[] = {(void*)&a0, (void*)&a1, (void*)&a2, (void*)&a3,
                        (void*)&a4, (void*)&a5, (void*)&a6, (void*)&a7};
        hipLaunchCooperativeKernel((const void*)lstm_tag_kernel, dim3(128), dim3(512), args, 148480, stream);
    }

    xproj2_kernel<<<dim3(100, 16, 2), 256, 0, stream>>>(hs0, wi1f, wi1b,
        b_ih_l1f, b_hh_l1f, b_ih_l1b, b_hh_l1b, gates_f, gates_b, 1024);

    {
        const float* a0 = gates_f; const float* a1 = gates_b;
        const _Float16* a2 = wp1f; const _Float16* a3 = wp1b;
        const int* a4 = Xlen; _Float16* a5 = hs1; unsigned* a6 = exbuf; int a7 = 128;
        void* args[] = {(void*)&a0, (void*)&a1, (void*)&a2, (void*)&a3,
                        (void*)&a4, (void*)&a5, (void*)&a6, (void*)&a7};
        hipLaunchCooperativeKernel((const void*)lstm_tag_kernel, dim3(128), dim3(512), args, 148480, stream);
    }

    ctx_kernel<<<dim3(32, 5), 256, 0, stream>>>(hs1, outW, outb, sel_b, sel_t, out);
    cls_kernel<<<KSEL, 256, 0, stream>>>(hs1, expW, expb, sel_b, sel_t, eidx, out);
}

// Round 9
// 1089.582 us; speedup vs baseline: 10.5433x; 1.0884x over previous
//
#include <hip/hip_runtime.h>
#include <hip/hip_bf16.h>

#define BB 64
#define TT 100
#define KSEL 2048
#define EMBD 300
#define EMBP 320
#define HH 512
#define GG 2048   // 4*H
#define NSYN 16

typedef __attribute__((ext_vector_type(8))) _Float16 f16x8;
typedef __attribute__((ext_vector_type(4))) _Float16 f16x4;
typedef __attribute__((ext_vector_type(4))) float f32x4;

__device__ __forceinline__ float sigf(float x) { return 1.f / (1.f + __expf(-x)); }
__device__ __forceinline__ float tanhfast(float x) {
    float e = __expf(-2.f * fabsf(x));
    float r = (1.f - e) / (1.f + e);
    return copysignf(r, x);
}

// ---------------- embedding gather -> fp16, rows in (t*64+b) order ----------------
__global__ void embed_kernel(const int* __restrict__ X, const float* __restrict__ emb,
                             _Float16* __restrict__ xemb) {
    int idx = blockIdx.x * blockDim.x + threadIdx.x;
    int total = BB * TT * EMBP;
    if (idx >= total) return;
    int row = idx / EMBP;
    int col = idx - row * EMBP;
    int b = row & 63, t = row >> 6;
    float v = 0.f;
    if (col < EMBD) v = emb[(size_t)X[b * TT + t] * EMBD + col];
    xemb[idx] = (_Float16)v;
}

// ---------------- W_hh -> fp16 permuted-row copy:  W'[n'][k] = W[pr(n')][k] ----------------
// pr(n') = (n'&3)*512 + (n'>>2)
__global__ void wprep_kernel(const float* __restrict__ w0f, const float* __restrict__ w0b,
                             const float* __restrict__ w1f, const float* __restrict__ w1b,
                             _Float16* __restrict__ o0f, _Float16* __restrict__ o0b,
                             _Float16* __restrict__ o1f, _Float16* __restrict__ o1b) {
    int bid = blockIdx.x;          // 256 blocks
    int mat = bid >> 6;
    int rgrp = (bid & 63) * 32;
    const float* W = mat == 0 ? w0f : mat == 1 ? w0b : mat == 2 ? w1f : w1b;
    _Float16* O = mat == 0 ? o0f : mat == 1 ? o0b : mat == 2 ? o1f : o1b;
    int tid = threadIdx.x;
    int rl = tid >> 3;
    int kc = (tid & 7) * 64;
    int np = rgrp + rl;
    int pr = (np & 3) * 512 + (np >> 2);
    const float* src = W + (size_t)pr * 512 + kc;
    _Float16* dst = O + (size_t)np * 512 + kc;
    for (int i = 0; i < 64; i += 4) {
        float4 v = *(const float4*)(src + i);
        dst[i + 0] = (_Float16)v.x;
        dst[i + 1] = (_Float16)v.y;
        dst[i + 2] = (_Float16)v.z;
        dst[i + 3] = (_Float16)v.w;
    }
}

// ---------------- W_ih -> fp16 permuted [n'][Kpad] (zero-padded) ----------------
__global__ void wih_prep_kernel(const float* __restrict__ Wf, const float* __restrict__ Wb,
                                _Float16* __restrict__ Of, _Float16* __restrict__ Ob,
                                int Kreal, int Kpad) {
    int dir = blockIdx.y;
    const float* W = dir ? Wb : Wf;
    _Float16* O = dir ? Ob : Of;
    int total = 2048 * Kpad;
    for (int idx = blockIdx.x * 256 + threadIdx.x; idx < total; idx += gridDim.x * 256) {
        int np = idx / Kpad, k = idx - np * Kpad;
        int pr = (np & 3) * 512 + (np >> 2);
        O[idx] = (k < Kreal) ? (_Float16)W[(size_t)pr * Kreal + k] : (_Float16)0.f;
    }
}

// ---------------- MFMA fp16 input projection, 64x128 tile, f/b merged, fp16 gates out ----
// A fp16 [6400][Kpad] rows m = t*64+b; B = prepped fp16 W'[2048][Kpad].
// Output gatesT[t][n'][b] fp16. blockIdx: x = t, y = n-tile(128), z = dir.
__global__ void __launch_bounds__(256)
xproj2_kernel(const _Float16* __restrict__ A,
              const _Float16* __restrict__ Wpf, const _Float16* __restrict__ Wpb,
              const float* __restrict__ bihf, const float* __restrict__ bhhf,
              const float* __restrict__ bihb, const float* __restrict__ bhhb,
              _Float16* __restrict__ gTf, _Float16* __restrict__ gTb, int Kpad) {
    __shared__ _Float16 A_lds[64][40];
    __shared__ _Float16 B_lds[128][40];
    __shared__ float biasl[128];
    int tid = threadIdx.x;
    int t = blockIdx.x;
    int n0 = blockIdx.y * 128;
    int dir = blockIdx.z;
    const _Float16* W = dir ? Wpb : Wpf;
    const float* bih = dir ? bihb : bihf;
    const float* bhh = dir ? bhhb : bhhf;
    _Float16* gT = dir ? gTb : gTf;
    if (tid < 128) {
        int n = n0 + tid;
        int pr = (n & 3) * 512 + (n >> 2);
        biasl[tid] = bih[pr] + bhh[pr];
    }
    int w = tid >> 6, l = tid & 63;
    int ml = tid >> 2, kk0 = (tid & 3) * 8;
    f32x4 acc[2][4] = {};
    __syncthreads();
    for (int k0 = 0; k0 < Kpad; k0 += 32) {
        *(uint4*)&A_lds[ml][kk0] = *(const uint4*)(A + (size_t)(t * 64 + ml) * Kpad + k0 + kk0);
#pragma unroll
        for (int h = 0; h < 2; h++) {
            int idx = h * 256 + tid;
            int nl = idx >> 2, kb = (idx & 3) * 8;
            *(uint4*)&B_lds[nl][kb] = *(const uint4*)(W + (size_t)(n0 + nl) * Kpad + k0 + kb);
        }
        __syncthreads();
#pragma unroll
        for (int nt = 0; nt < 2; nt++) {
            f16x8 bfrag = *(const f16x8*)&B_lds[nt * 64 + w * 16 + (l & 15)][(l >> 4) * 8];
#pragma unroll
            for (int mb = 0; mb < 4; mb++) {
                f16x8 afrag = *(const f16x8*)&A_lds[mb * 16 + (l & 15)][(l >> 4) * 8];
                acc[nt][mb] = __builtin_amdgcn_mfma_f32_16x16x32_f16(afrag, bfrag, acc[nt][mb], 0, 0, 0);
            }
        }
        __syncthreads();
    }
#pragma unroll
    for (int nt = 0; nt < 2; nt++) {
        int n_local = nt * 64 + w * 16 + (l & 15);
        float bias = biasl[n_local];
#pragma unroll
        for (int mb = 0; mb < 4; mb++) {
            f16x4 st;
            st[0] = (_Float16)(acc[nt][mb][0] + bias);
            st[1] = (_Float16)(acc[nt][mb][1] + bias);
            st[2] = (_Float16)(acc[nt][mb][2] + bias);
            st[3] = (_Float16)(acc[nt][mb][3] + bias);
            *(f16x4*)&gT[((size_t)t * 2048 + n0 + n_local) * 64 + mb * 16 + (l >> 4) * 4] = st;
        }
    }
}

// ---------------- bilstm layer: R6-proven protocol; two-phase poll; fp16 gates ----------
// 128 wgs x 512 thr (cooperative). g = bid&7: dir = g&1, bg = g>>1. member = bid>>3 owns
// 128 n'-cols (W-slice 128KB in LDS). Exchange word u32 = (fp16 h)<<16 | tag, relaxed
// SYSTEM atomics, 2-slot ring ex[slot][g][16 b][512 j]. No fences anywhere.
// Poll: phase 1 spins on ONE word/thread (16x less L3 traffic) + s_sleep; phase 2 does the
// full 16-word check and falls back to the full spin if stale (worst case == R6 loop).
__global__ void __launch_bounds__(512, 1)
lstm_tag_kernel(const _Float16* __restrict__ gTf, const _Float16* __restrict__ gTb,
                const _Float16* __restrict__ wpf, const _Float16* __restrict__ wpb,
                const int* __restrict__ lengths, _Float16* __restrict__ hs,
                unsigned* __restrict__ ex, int tagbase) {
    extern __shared__ char smem[];
    uint4* wlds = (uint4*)smem;                       // 131072 B: [128 c][64 gi] swizzled
    uint4* hlds = (uint4*)(smem + 131072);            // 16384 B:  [16 b][64 gi] swizzled
    _Float16* hpack = (_Float16*)(smem + 147456);     // 1024 B:   [16 b][32 jl]
    int bid = blockIdx.x;
    int g = bid & 7, mem = bid >> 3;
    int dir = g & 1, bg = g >> 1;
    const _Float16* gT = dir ? gTb : gTf;
    const _Float16* wp = dir ? wpb : wpf;
    int tid = threadIdx.x;
    int w = tid >> 6, l = tid & 63;
    int lc = l & 15, hi = l >> 4;
    int q = lc & 3;
    int nb = mem * 128;
    int c = w * 16 + lc;                 // member-local col 0..127

    // ---- stage W-slice into LDS (once), XOR-swizzled granules ----
    {
        const _Float16* wsrc = wp + (size_t)nb * 512;
        for (int i = 0; i < 16; i++) {
            int idx = i * 512 + tid;
            int cc = idx >> 6, gi = idx & 63;
            uint4 v = *(const uint4*)(wsrc + (size_t)cc * 512 + gi * 8);
            wlds[(cc << 6) | (gi ^ (cc & 7))] = v;
        }
    }
    float cst[4] = {};
    float hst[4] = {};
    int lenv[4];
#pragma unroll
    for (int r = 0; r < 4; r++) lenv[r] = lengths[bg * 16 + hi * 4 + r];
    __syncthreads();

    for (int s = 0; s < TT; s++) {
        int t = dir ? (TT - 1 - s) : s;
        // gate init (fp16, 8B/thread; issued before poll)
        f32x4 acc, acc2;
        {
            f16x4 gv = *(const f16x4*)(gT + ((size_t)t * 2048 + nb + c) * 64 + bg * 16 + hi * 4);
            acc[0] = (float)gv[0]; acc[1] = (float)gv[1];
            acc[2] = (float)gv[2]; acc[3] = (float)gv[3];
            acc2[0] = 0.f; acc2[1] = 0.f; acc2[2] = 0.f; acc2[3] = 0.f;
        }
        if (s > 0) {
            // ---- two-phase tagged poll: (b=i, j=tid) for i in 0..15 ----
            const unsigned* exrow = ex + ((size_t)(((s - 1) & 1) * 8 + g) * 16) * 512;
            unsigned want = (unsigned)(tagbase + s);
            unsigned vals[16];
            int sentinel = tid & 15;
            // phase 1: cheap spin on one word
            while (true) {
                unsigned v = __hip_atomic_load(exrow + sentinel * 512 + tid, __ATOMIC_RELAXED,
                                               __HIP_MEMORY_SCOPE_SYSTEM);
                if ((v & 0xFFFFu) == want) break;
                __builtin_amdgcn_s_sleep(2);
            }
            // phase 2: full check, fall back to full spin if any word stale
            while (true) {
                bool ok = true;
#pragma unroll
                for (int i = 0; i < 16; i++)
                    vals[i] = __hip_atomic_load(exrow + i * 512 + tid, __ATOMIC_RELAXED,
                                                __HIP_MEMORY_SCOPE_SYSTEM);
#pragma unroll
                for (int i = 0; i < 16; i++) ok &= ((vals[i] & 0xFFFFu) == want);
                if (ok) break;
            }
            // ---- stage payloads into swizzled hlds ----
            {
                _Float16* hf = (_Float16*)hlds;
                int gi = tid >> 3, el = tid & 7;
#pragma unroll
                for (int i = 0; i < 16; i++) {
                    unsigned short hb = (unsigned short)(vals[i] >> 16);
                    hf[(((i << 6) | (gi ^ (i & 7))) << 3) + el] = __builtin_bit_cast(_Float16, hb);
                }
            }
            __syncthreads();
            // ---- MFMA: 16 k-slices, two independent 8-deep chains ----
#pragma unroll
            for (int ks = 0; ks < 16; ks += 2) {
                int gg0 = ks * 4 + hi;
                int gg1 = (ks + 1) * 4 + hi;
                f16x8 af0 = *(const f16x8*)((const char*)hlds + (((lc << 6) | (gg0 ^ (lc & 7))) << 4));
                f16x8 bf0 = *(const f16x8*)((const char*)wlds + (((c << 6) | (gg0 ^ (lc & 7))) << 4));
                f16x8 af1 = *(const f16x8*)((const char*)hlds + (((lc << 6) | (gg1 ^ (lc & 7))) << 4));
                f16x8 bf1 = *(const f16x8*)((const char*)wlds + (((c << 6) | (gg1 ^ (lc & 7))) << 4));
                acc  = __builtin_amdgcn_mfma_f32_16x16x32_f16(af0, bf0, acc, 0, 0, 0);
                acc2 = __builtin_amdgcn_mfma_f32_16x16x32_f16(af1, bf1, acc2, 0, 0, 0);
            }
            acc[0] += acc2[0]; acc[1] += acc2[1]; acc[2] += acc2[2]; acc[3] += acc2[3];
            __syncthreads();   // MFMA readers done before next step's hlds overwrite
        }
        // ---- epilogue: 4-lane gate transpose + state update ----
#pragma unroll
        for (int r = 0; r < 4; r++) {
            float pre = acc[r];
            float sg = sigf(pre), th = tanhfast(pre);
            float a = (q == 2) ? th : sg;
            float p1 = __shfl_xor(a, 1);
            float p2 = __shfl_xor(a, 2);
            float p3 = __shfl_xor(p1, 2);
            float gi_ = q == 0 ? a : q == 1 ? p1 : q == 2 ? p2 : p3;
            float gf_ = q == 0 ? p1 : q == 1 ? a : q == 2 ? p3 : p2;
            float gg_ = q == 0 ? p2 : q == 1 ? p3 : q == 2 ? a : p1;
            float go_ = q == 0 ? p3 : q == 1 ? p2 : q == 2 ? p1 : a;
            float cn = gf_ * cst[r] + gi_ * gg_;
            float hn = go_ * tanhfast(cn);
            if (t < lenv[r]) { cst[r] = cn; hst[r] = hn; }
            if (q == 0) hpack[(hi * 4 + r) * 32 + w * 4 + (lc >> 2)] = (_Float16)hst[r];
        }
        __syncthreads();
        // ---- publish: 1 tagged u32 + 1 plain fp16 per thread ----
        {
            int bb = tid >> 5, jl = tid & 31;
            _Float16 hv = hpack[bb * 32 + jl];
            unsigned wv = ((unsigned)__builtin_bit_cast(unsigned short, hv) << 16)
                        | (unsigned)(tagbase + s + 1);
            __hip_atomic_store(ex + (((size_t)(s & 1) * 8 + g) * 16 + bb) * 512 + mem * 32 + jl,
                               wv, __ATOMIC_RELAXED, __HIP_MEMORY_SCOPE_SYSTEM);
            hs[((size_t)(t * 64 + bg * 16 + bb)) * 1024 + dir * 512 + mem * 32 + jl] = hv;
        }
        __syncthreads();
    }
}

// ---------------- ctx = xsel @ out_W^T + out_b ----------------
__global__ void ctx_kernel(const _Float16* __restrict__ hs1, const float* __restrict__ outW,
                           const float* __restrict__ outb, const int* __restrict__ sel_b,
                           const int* __restrict__ sel_t, float* __restrict__ out) {
    __shared__ float As[16][68];
    __shared__ float Bs[16][68];
    __shared__ int rowbase[64];
    int tid = threadIdx.x;
    int m0 = blockIdx.x * 64, n0 = blockIdx.y * 64;
    if (tid < 64) {
        int m = m0 + tid;
        rowbase[tid] = (sel_t[m] * 64 + sel_b[m]) * 1024;
    }
    __syncthreads();
    int tx = tid & 15, ty = tid >> 4;
    float acc[4][4] = {};
    for (int k0 = 0; k0 < 1024; k0 += 16) {
        for (int e = tid; e < 1024; e += 256) {
            int ml = e >> 4, k = e & 15;
            As[k][ml] = (float)hs1[(size_t)rowbase[ml] + k0 + k];
        }
        for (int e = tid; e < 1024; e += 256) {
            int nl = e >> 4, k = e & 15;
            int n = n0 + nl;
            Bs[k][nl] = (n < EMBD) ? outW[(size_t)n * 1024 + k0 + k] : 0.f;
        }
        __syncthreads();
#pragma unroll
        for (int kk = 0; kk < 16; kk++) {
            float4 a4 = *(const float4*)&As[kk][ty * 4];
            float4 b4 = *(const float4*)&Bs[kk][tx * 4];
            float av[4] = {a4.x, a4.y, a4.z, a4.w};
            float bv[4] = {b4.x, b4.y, b4.z, b4.w};
#pragma unroll
            for (int i = 0; i < 4; i++)
#pragma unroll
                for (int jj = 0; jj < 4; jj++) acc[i][jj] += av[i] * bv[jj];
        }
        __syncthreads();
    }
    for (int i = 0; i < 4; i++) {
        int m = m0 + ty * 4 + i;
        for (int jj = 0; jj < 4; jj++) {
            int n = n0 + tx * 4 + jj;
            if (n < EMBD) out[(size_t)m * EMBD + n] = acc[i][jj] + outb[n];
        }
    }
}

// ---------------- cls = einsum('ksd,kd->ks', exp_W[eidx], xsel) + exp_b[eidx] ----------------
__global__ void cls_kernel(const _Float16* __restrict__ hs1, const float* __restrict__ expW,
                           const float* __restrict__ expb, const int* __restrict__ sel_b,
                           const int* __restrict__ sel_t, const int* __restrict__ eidx,
                           float* __restrict__ out) {
    __shared__ float xr[1024];
    int r = blockIdx.x;
    int tid = threadIdx.x;
    int e = eidx[r];
    int base = (sel_t[r] * 64 + sel_b[r]) * 1024;
    for (int qq = tid; qq < 1024; qq += 256) xr[qq] = (float)hs1[(size_t)base + qq];
    __syncthreads();
    int lane = tid & 63, wid = tid >> 6;
    for (int p = 0; p < 4; p++) {
        int s = p * 4 + wid;
        const float* wrow = expW + ((size_t)e * NSYN + s) * 1024;
        float partial = 0.f;
#pragma unroll
        for (int i = 0; i < 16; i++) {
            int k = lane + 64 * i;
            partial += xr[k] * wrow[k];
        }
        for (int off = 32; off; off >>= 1) partial += __shfl_down(partial, off);
        if (lane == 0) out[(size_t)KSEL * EMBD + (size_t)r * NSYN + s] = partial + expb[e * NSYN + s];
    }
}

extern "C" void kernel_launch(void* const* d_in, const int* in_sizes, int n_in,
                              void* d_out, int out_size, void* d_ws, size_t ws_size,
                              hipStream_t stream) {
    const int* X = (const int*)d_in[0];
    const int* Xlen = (const int*)d_in[1];
    const int* sel_b = (const int*)d_in[2];
    const int* sel_t = (const int*)d_in[3];
    const int* eidx = (const int*)d_in[4];
    const float* emb = (const float*)d_in[5];
    const float* w_ih_l0f = (const float*)d_in[6];
    const float* w_hh_l0f = (const float*)d_in[7];
    const float* b_ih_l0f = (const float*)d_in[8];
    const float* b_hh_l0f = (const float*)d_in[9];
    const float* w_ih_l0b = (const float*)d_in[10];
    const float* w_hh_l0b = (const float*)d_in[11];
    const float* b_ih_l0b = (const float*)d_in[12];
    const float* b_hh_l0b = (const float*)d_in[13];
    const float* w_ih_l1f = (const float*)d_in[14];
    const float* w_hh_l1f = (const float*)d_in[15];
    const float* b_ih_l1f = (const float*)d_in[16];
    const float* b_hh_l1f = (const float*)d_in[17];
    const float* w_ih_l1b = (const float*)d_in[18];
    const float* w_hh_l1b = (const float*)d_in[19];
    const float* b_ih_l1b = (const float*)d_in[20];
    const float* b_hh_l1b = (const float*)d_in[21];
    const float* outW = (const float*)d_in[22];
    const float* outb = (const float*)d_in[23];
    const float* expW = (const float*)d_in[24];
    const float* expb = (const float*)d_in[25];

    char* ws = (char*)d_ws;
    _Float16* gates_f = (_Float16*)ws;                            // 26,214,400 B  [t][n'][b] fp16
    _Float16* gates_b = (_Float16*)(ws + 26214400);               // 26,214,400 B
    _Float16* wp0f = (_Float16*)(ws + 52428800);                  // 2,097,152 B each
    _Float16* wp0b = (_Float16*)(ws + 54525952);
    _Float16* wp1f = (_Float16*)(ws + 56623104);
    _Float16* wp1b = (_Float16*)(ws + 58720256);
    _Float16* hs0  = (_Float16*)(ws + 60817408);                  // 13,107,200 B  [(t*64+b)][1024]
    _Float16* hs1  = (_Float16*)(ws + 73924608);                  // 13,107,200 B
    _Float16* xemb = (_Float16*)(ws + 87031808);                  // 4,096,000 B
    unsigned* exbuf = (unsigned*)(ws + 91127808);                 // 524,288 B (2-slot tagged ring)
    _Float16* wi0f = (_Float16*)(ws + 91652096);                  // 1,310,720 B  [2048][320]
    _Float16* wi0b = (_Float16*)(ws + 92962816);                  // 1,310,720 B
    _Float16* wi1f = (_Float16*)(ws + 94273536);                  // 4,194,304 B  [2048][1024]
    _Float16* wi1b = (_Float16*)(ws + 98467840);                  // 4,194,304 B
    size_t needed = 102662144;
    if (ws_size < needed) return;  // diagnostic: absmax would equal max|ref|
    float* out = (float*)d_out;

    hipFuncSetAttribute((const void*)lstm_tag_kernel,
                        hipFuncAttributeMaxDynamicSharedMemorySize, 148480);

    hipMemsetAsync(exbuf, 0, 524288, stream);   // clear tags (replay-safe)

    embed_kernel<<<(BB * TT * EMBP + 255) / 256, 256, 0, stream>>>(X, emb, xemb);
    wprep_kernel<<<256, 256, 0, stream>>>(w_hh_l0f, w_hh_l0b, w_hh_l1f, w_hh_l1b,
                                          wp0f, wp0b, wp1f, wp1b);
    wih_prep_kernel<<<dim3(512, 2), 256, 0, stream>>>(w_ih_l0f, w_ih_l0b, wi0f, wi0b, EMBD, EMBP);
    wih_prep_kernel<<<dim3(512, 2), 256, 0, stream>>>(w_ih_l1f, w_ih_l1b, wi1f, wi1b, 1024, 1024);

    xproj2_kernel<<<dim3(100, 16, 2), 256, 0, stream>>>(xemb, wi0f, wi0b,
        b_ih_l0f, b_hh_l0f, b_ih_l0b, b_hh_l0b, gates_f, gates_b, EMBP);

    {
        const _Float16* a0 = gates_f; const _Float16* a1 = gates_b;
        const _Float16* a2 = wp0f; const _Float16* a3 = wp0b;
        const int* a4 = Xlen; _Float16* a5 = hs0; unsigned* a6 = exbuf; int a7 = 0;
        void* args[] = {(void*)&a0, (void*)&a1, (void*)&a2, (void*)&a3,
                        (void*)&a4, (void*)&a5, (void*)&a6, (void*)&a7};
        hipLaunchCooperativeKernel((const void*)lstm_tag_kernel, dim3(128), dim3(512), args, 148480, stream);
    }

    xproj2_kernel<<<dim3(100, 16, 2), 256, 0, stream>>>(hs0, wi1f, wi1b,
        b_ih_l1f, b_hh_l1f, b_ih_l1b, b_hh_l1b, gates_f, gates_b, 1024);

    {
        const _Float16* a0 = gates_f; const _Float16* a1 = gates_b;
        const _Float16* a2 = wp1f; const _Float16* a3 = wp1b;
        const int* a4 = Xlen; _Float16* a5 = hs1; unsigned* a6 = exbuf; int a7 = 128;
        void* args[] = {(void*)&a0, (void*)&a1, (void*)&a2, (void*)&a3,
                        (void*)&a4, (void*)&a5, (void*)&a6, (void*)&a7};
        hipLaunchCooperativeKernel((const void*)lstm_tag_kernel, dim3(128), dim3(512), args, 148480, stream);
    }

    ctx_kernel<<<dim3(32, 5), 256, 0, stream>>>(hs1, outW, outb, sel_b, sel_t, out);
    cls_kernel<<<KSEL, 256, 0, stream>>>(hs1, expW, expb, sel_b, sel_t, eidx, out);
}